// Round 3
// baseline (462.761 us; speedup 1.0000x reference)
//
#include <hip/hip_runtime.h>
#include <math.h>

#define NNODES 50000
#define NEDGES 800000
#define NPAD   50048   // 782 * 64

typedef unsigned int uint;
typedef unsigned short u16;
typedef __bf16 bf16x8 __attribute__((ext_vector_type(8)));
typedef float f32x4 __attribute__((ext_vector_type(4)));

__device__ __forceinline__ float lrelu(float x){ return x > 0.f ? x : 0.2f*x; }
__device__ __forceinline__ float elu_f(float x){ return x > 0.f ? x : expm1f(x); }
__device__ __forceinline__ u16 f2bf(float f){
    uint u = __float_as_uint(f);
    return (u16)((u + 0x7fffu + ((u >> 16) & 1u)) >> 16);
}
__device__ __forceinline__ float bf2f(u16 h){ return __uint_as_float(((uint)h) << 16); }
__device__ __forceinline__ float blo(uint u){ return __uint_as_float(u << 16); }
__device__ __forceinline__ float bhi(uint u){ return __uint_as_float(u & 0xffff0000u); }

// ================= input splitting =================
// x [N][128] f32 -> Xh/Xl ushort [NPAD][128], pad rows zeroed
__global__ void split_x(const float* __restrict__ x, u16* __restrict__ Xh, u16* __restrict__ Xl, int N)
{
    int idx = blockIdx.x * blockDim.x + threadIdx.x;       // one float4 per thread
    if (idx >= NPAD * 32) return;
    int n = idx >> 5;
    float4 v = make_float4(0.f, 0.f, 0.f, 0.f);
    if (n < N) v = ((const float4*)x)[idx];
    ushort4 h, l;
    h.x = f2bf(v.x); l.x = f2bf(v.x - bf2f(h.x));
    h.y = f2bf(v.y); l.y = f2bf(v.y - bf2f(h.y));
    h.z = f2bf(v.z); l.z = f2bf(v.z - bf2f(h.z));
    h.w = f2bf(v.w); l.w = f2bf(v.w - bf2f(h.w));
    ((ushort4*)Xh)[idx] = h;
    ((ushort4*)Xl)[idx] = l;
}

// W [128][Cc] f32 -> Bt hi/lo ushort [CP][128] (transposed, col-padded with zeros)
__global__ void split_w(const float* __restrict__ W, u16* __restrict__ Bh, u16* __restrict__ Bl, int Cc, int CP)
{
    int idx = blockIdx.x * blockDim.x + threadIdx.x;       // idx = col*128 + k
    if (idx >= CP * 128) return;
    int col = idx >> 7, k = idx & 127;
    float v = (col < Cc) ? W[k * Cc + col] : 0.f;
    u16 h = f2bf(v);
    Bh[idx] = h;
    Bl[idx] = f2bf(v - bf2f(h));
}

__global__ void zero_pad2(u16* __restrict__ Hh, u16* __restrict__ Hl)
{
    int idx = blockIdx.x * blockDim.x + threadIdx.x;       // (NPAD-NNODES)*128 = 6144
    if (idx < (NPAD - NNODES) * 128) {
        Hh[(size_t)NNODES * 128 + idx] = 0;
        Hl[(size_t)NNODES * 128 + idx] = 0;
    }
}

// ================= GEMM: C[N,Cc] = A[N,128] @ B[128,Cc], LDS-free MFMA =================
// A pre-split hi/lo [NPAD][128] ushort; B pre-split transposed [CP][128] ushort.
// BM=64, BN=128, 4 waves (2 rows x 2 cols), wave tile 32x64. grid = (782, ceil(Cc/128)).
template<bool OUTBF>
__global__ __launch_bounds__(256)
void gemm_mfma(const u16* __restrict__ Ah, const u16* __restrict__ Al,
               const u16* __restrict__ Bh, const u16* __restrict__ Bl,
               void* __restrict__ Cout, int N, int Cc)
{
    const int bm = blockIdx.x * 64, bn = blockIdx.y * 128;
    const int tid = threadIdx.x, wid = tid >> 6, lane = tid & 63;
    const int lr = lane & 15, lk = (lane >> 4) << 3;
    const int wr = (wid & 1) * 32, wc = (wid >> 1) * 64;
    f32x4 acc[2][4] = {};

    #pragma unroll
    for (int kt = 0; kt < 128; kt += 32) {
        bf16x8 aH[2], aL[2], bH[4], bL[4];
        #pragma unroll
        for (int fr = 0; fr < 2; fr++) {
            size_t off = (size_t)(bm + wr + fr*16 + lr) * 128 + kt + lk;
            aH[fr] = *(const bf16x8*)(Ah + off);
            aL[fr] = *(const bf16x8*)(Al + off);
        }
        #pragma unroll
        for (int fs = 0; fs < 4; fs++) {
            size_t off = (size_t)(bn + wc + fs*16 + lr) * 128 + kt + lk;
            bH[fs] = *(const bf16x8*)(Bh + off);
            bL[fs] = *(const bf16x8*)(Bl + off);
        }
        #pragma unroll
        for (int fr = 0; fr < 2; fr++)
            #pragma unroll
            for (int fs = 0; fs < 4; fs++) {
                acc[fr][fs] = __builtin_amdgcn_mfma_f32_16x16x32_bf16(aH[fr], bH[fs], acc[fr][fs], 0, 0, 0);
                acc[fr][fs] = __builtin_amdgcn_mfma_f32_16x16x32_bf16(aH[fr], bL[fs], acc[fr][fs], 0, 0, 0);
                acc[fr][fs] = __builtin_amdgcn_mfma_f32_16x16x32_bf16(aL[fr], bH[fs], acc[fr][fs], 0, 0, 0);
            }
    }
    // D mapping: col = lane&15, row = (lane>>4)*4 + v
    #pragma unroll
    for (int fr = 0; fr < 2; fr++)
        #pragma unroll
        for (int fs = 0; fs < 4; fs++) {
            int col = bn + wc + fs*16 + lr;
            if (col >= Cc) continue;
            #pragma unroll
            for (int v = 0; v < 4; v++) {
                int row = bm + wr + fr*16 + ((lane >> 4) << 2) + v;
                if (row < N) {
                    if (OUTBF) ((u16*)Cout)[(size_t)row * Cc + col] = f2bf(acc[fr][fs][v]);
                    else       ((float*)Cout)[(size_t)row * Cc + col] = acc[fr][fs][v];
                }
            }
        }
}

// ================= el/er from bf16 ft =================
template<int C, int D>
__global__ void compute_elr(const uint* __restrict__ ftb, const float* __restrict__ al,
                            const float* __restrict__ ar, float* __restrict__ el,
                            float* __restrict__ er, int N)
{
    int wv = threadIdx.x >> 6, lane = threadIdx.x & 63;
    int n = blockIdx.x * 4 + wv;
    if (n >= N) return;
    const uint* row = ftb + (size_t)n * (C/2);
    float l0=0.f, l1=0.f, r0=0.f, r1=0.f;
    for (int p = lane; p < C/2; p += 64) {
        uint u = row[p];
        float f0 = blo(u), f1 = bhi(u);
        int c0 = 2*p, c1 = 2*p + 1;
        float a0 = al[c0], a1 = al[c1], g0 = ar[c0], g1 = ar[c1];
        if (c0 < D) { l0 += f0*a0; r0 += f0*g0; } else { l1 += f0*a0; r1 += f0*g0; }
        if (c1 < D) { l0 += f1*a1; r0 += f1*g1; } else { l1 += f1*a1; r1 += f1*g1; }
    }
    #pragma unroll
    for (int off = 32; off; off >>= 1) {
        l0 += __shfl_down(l0, off); l1 += __shfl_down(l1, off);
        r0 += __shfl_down(r0, off); r1 += __shfl_down(r1, off);
    }
    if (lane == 0) { el[2*n] = l0; el[2*n+1] = l1; er[2*n] = r0; er[2*n+1] = r1; }
}

// ================= CSR build =================
__global__ void hist_kernel(const int* __restrict__ dst, int* __restrict__ counts, int E)
{
    int i = blockIdx.x * blockDim.x + threadIdx.x;
    if (i < E) atomicAdd(&counts[dst[i]], 1);
}

__global__ __launch_bounds__(1024)
void scan_kernel(const int* __restrict__ counts, int* __restrict__ row_start, int n)
{
    __shared__ int wsum[16];
    __shared__ int s_carry;
    const int tid = threadIdx.x, lane = tid & 63, wv = tid >> 6;
    if (tid == 0) { s_carry = 0; row_start[0] = 0; }
    __syncthreads();
    for (int base = 0; base < n; base += 4096) {
        int i0 = base + tid*4;
        int v[4];
        #pragma unroll
        for (int j = 0; j < 4; j++) { int i = i0 + j; v[j] = (i < n) ? counts[i] : 0; }
        v[1] += v[0]; v[2] += v[1]; v[3] += v[2];
        int t = v[3];
        #pragma unroll
        for (int off = 1; off < 64; off <<= 1) {
            int u = __shfl_up(t, off);
            if (lane >= off) t += u;
        }
        int wtot = __shfl(t, 63);
        int texcl = t - v[3];
        if (lane == 63) wsum[wv] = wtot;
        __syncthreads();
        int woff = 0;
        for (int w = 0; w < 16; w++) if (w < wv) woff += wsum[w];
        int basev = s_carry + woff + texcl;
        #pragma unroll
        for (int j = 0; j < 4; j++) { int i = i0 + j; if (i < n) row_start[i+1] = basev + v[j]; }
        __syncthreads();
        if (tid == 0) {
            int tot = 0;
            for (int w = 0; w < 16; w++) tot += wsum[w];
            s_carry += tot;
        }
        __syncthreads();
    }
}

__global__ void scatter_kernel(const int* __restrict__ src, const int* __restrict__ dst,
                               const int* __restrict__ row_start, int* __restrict__ cursor,
                               int* __restrict__ src_sorted, int E)
{
    int i = blockIdx.x * blockDim.x + threadIdx.x;
    if (i < E) {
        int d = dst[i];
        int p = atomicAdd(&cursor[d], 1);
        src_sorted[row_start[d] + p] = src[i];
    }
}

// ================= aggregation, C=128 layers: one wave per dst node =================
// MODE 0: no res, ELU, write h f32 + hi/lo split. MODE 1: identity res, ELU, write hi/lo only.
template<int MODE>
__global__ __launch_bounds__(256)
void gat_agg128(const uint* __restrict__ ftb, const float* __restrict__ el,
                const float* __restrict__ er, const int* __restrict__ row_start,
                const int* __restrict__ ssorted, const float* __restrict__ res,
                const float* __restrict__ bias, float* __restrict__ hout,
                u16* __restrict__ Hh, u16* __restrict__ Hl)
{
    __shared__ int   s_src[4][64];
    __shared__ float s_w[4][2][64];
    const int wv = threadIdx.x >> 6, lane = threadIdx.x & 63;
    const int n = blockIdx.x * 4 + wv;
    const int beg = row_start[n];
    const int deg = row_start[n+1] - beg;
    const float2 ern = *(const float2*)(er + 2*(size_t)n);
    const int h = lane >> 5;
    float ax = 0.f, ay = 0.f, dp0 = 0.f, dp1 = 0.f;

    for (int cb = 0; cb < deg; cb += 64) {
        const int cnt = min(64, deg - cb);
        float w0 = 0.f, w1 = 0.f; int s = 0;
        if (lane < cnt) {
            s = ssorted[beg + cb + lane];
            float2 e = *(const float2*)(el + 2*(size_t)s);
            w0 = __expf(lrelu(e.x + ern.x));     // no max subtraction: |logit| <= ~6
            w1 = __expf(lrelu(e.y + ern.y));
        }
        dp0 += w0; dp1 += w1;
        s_src[wv][lane] = s; s_w[wv][0][lane] = w0; s_w[wv][1][lane] = w1;
        asm volatile("s_waitcnt lgkmcnt(0)" ::: "memory");   // wave-synchronous LDS publish
        int t = 0;
        for (; t + 4 <= cnt; t += 4) {
            int4   s4 = *(const int4*)&s_src[wv][t];
            float4 w4 = *(const float4*)&s_w[wv][h][t];
            uint u0 = ftb[(size_t)s4.x * 64 + lane];
            uint u1 = ftb[(size_t)s4.y * 64 + lane];
            uint u2 = ftb[(size_t)s4.z * 64 + lane];
            uint u3 = ftb[(size_t)s4.w * 64 + lane];
            ax += w4.x*blo(u0); ay += w4.x*bhi(u0);
            ax += w4.y*blo(u1); ay += w4.y*bhi(u1);
            ax += w4.z*blo(u2); ay += w4.z*bhi(u2);
            ax += w4.w*blo(u3); ay += w4.w*bhi(u3);
        }
        for (; t < cnt; t++) {
            int sv = s_src[wv][t];
            float w = s_w[wv][h][t];
            uint u = ftb[(size_t)sv * 64 + lane];
            ax += w*blo(u); ay += w*bhi(u);
        }
    }
    #pragma unroll
    for (int off = 32; off; off >>= 1) { dp0 += __shfl_xor(dp0, off); dp1 += __shfl_xor(dp1, off); }
    const float den = (h == 0) ? dp0 : dp1;
    float r0 = (deg > 0) ? ax / den : 0.f;
    float r1 = (deg > 0) ? ay / den : 0.f;
    const int c0 = 2 * lane;
    const float2 bv = *(const float2*)(bias + c0);
    float v0 = r0 + bv.x, v1 = r1 + bv.y;
    if (MODE == 1) {
        float2 rv = *(const float2*)(res + (size_t)n*128 + c0);
        v0 += rv.x; v1 += rv.y;
    }
    v0 = elu_f(v0); v1 = elu_f(v1);
    if (MODE == 0) *(float2*)(hout + (size_t)n*128 + c0) = make_float2(v0, v1);
    u16 h0 = f2bf(v0), h1v = f2bf(v1);
    size_t ob = (size_t)n*128 + c0;
    ushort2 hh = make_ushort2(h0, h1v);
    ushort2 ll = make_ushort2(f2bf(v0 - bf2f(h0)), f2bf(v1 - bf2f(h1v)));
    *(ushort2*)&Hh[ob] = hh;
    *(ushort2*)&Hl[ob] = ll;
}

// ================= output-layer aggregation: one wave per dst node, C=194 D=97 =================
__global__ __launch_bounds__(256)
void gat_agg_out(const uint* __restrict__ ftb, const float* __restrict__ el,
                 const float* __restrict__ er, const int* __restrict__ row_start,
                 const int* __restrict__ ssorted, const float* __restrict__ res,
                 const float* __restrict__ bias, float* __restrict__ out)
{
    __shared__ int   s_src[4][64];
    __shared__ float s_w[4][2][64];
    __shared__ float s_a1[4][97];
    const int wv = threadIdx.x >> 6, lane = threadIdx.x & 63;
    const int n = blockIdx.x * 4 + wv;
    if (n >= NNODES - 1) return;                 // wave-uniform exit, no barriers used
    const int beg = row_start[n];
    const int deg = row_start[n+1] - beg;
    const float2 ern = *(const float2*)(er + 2*(size_t)n);
    const bool dual = (lane < 33);               // lane owns u32 p1=lane and p2=64+lane (if dual)
    const bool xh0 = (lane <= 48), yh0 = (lane <= 47);  // head of cols 2*lane, 2*lane+1
    float ax1=0.f, ay1=0.f, ax2=0.f, ay2=0.f, dp0=0.f, dp1=0.f;

    for (int cb = 0; cb < deg; cb += 64) {
        const int cnt = min(64, deg - cb);
        float w0 = 0.f, w1 = 0.f; int s = 0;
        if (lane < cnt) {
            s = ssorted[beg + cb + lane];
            float2 e = *(const float2*)(el + 2*(size_t)s);
            w0 = __expf(lrelu(e.x + ern.x));
            w1 = __expf(lrelu(e.y + ern.y));
        }
        dp0 += w0; dp1 += w1;
        s_src[wv][lane] = s; s_w[wv][0][lane] = w0; s_w[wv][1][lane] = w1;
        asm volatile("s_waitcnt lgkmcnt(0)" ::: "memory");
        int t = 0;
        for (; t + 4 <= cnt; t += 4) {
            int4   s4 = *(const int4*)&s_src[wv][t];
            float4 q0 = *(const float4*)&s_w[wv][0][t];
            float4 q1 = *(const float4*)&s_w[wv][1][t];
            #pragma unroll
            for (int j = 0; j < 4; j++) {
                int sv = (j==0) ? s4.x : (j==1) ? s4.y : (j==2) ? s4.z : s4.w;
                float f0 = (j==0) ? q0.x : (j==1) ? q0.y : (j==2) ? q0.z : q0.w;
                float f1 = (j==0) ? q1.x : (j==1) ? q1.y : (j==2) ? q1.z : q1.w;
                const uint* row = ftb + (size_t)sv * 97;
                uint u1 = row[lane];
                uint u2 = dual ? row[64 + lane] : 0u;
                float wx = xh0 ? f0 : f1, wy = yh0 ? f0 : f1;
                ax1 += wx*blo(u1); ay1 += wy*bhi(u1);
                ax2 += f1*blo(u2); ay2 += f1*bhi(u2);
            }
        }
        for (; t < cnt; t++) {
            int sv = s_src[wv][t];
            float f0 = s_w[wv][0][t], f1 = s_w[wv][1][t];
            const uint* row = ftb + (size_t)sv * 97;
            uint u1 = row[lane];
            uint u2 = dual ? row[64 + lane] : 0u;
            float wx = xh0 ? f0 : f1, wy = yh0 ? f0 : f1;
            ax1 += wx*blo(u1); ay1 += wy*bhi(u1);
            ax2 += f1*blo(u2); ay2 += f1*bhi(u2);
        }
    }
    #pragma unroll
    for (int off = 32; off; off >>= 1) { dp0 += __shfl_xor(dp0, off); dp1 += __shfl_xor(dp1, off); }
    const float i0 = (deg > 0) ? 1.f/dp0 : 0.f;
    const float i1 = (deg > 0) ? 1.f/dp1 : 0.f;
    float A0x = ax1 * (xh0 ? i0 : i1);
    float A0y = ay1 * (yh0 ? i0 : i1);
    float A2x = ax2 * i1, A2y = ay2 * i1;
    // scatter head-1 aggregates (head1 col index c' = col - 97) into per-wave LDS
    if (lane == 48)      s_a1[wv][0] = A0y;
    else if (lane >= 49) { s_a1[wv][2*lane - 97] = A0x; s_a1[wv][2*lane - 96] = A0y; }
    if (dual)            { s_a1[wv][31 + 2*lane] = A2x; s_a1[wv][32 + 2*lane] = A2y; }
    asm volatile("s_waitcnt lgkmcnt(0)" ::: "memory");
    if (lane <= 48) {
        const int c = 2 * lane;
        const float* rr = res + (size_t)n * 194;
        out[(size_t)n*97 + c] = 0.5f*(A0x + s_a1[wv][c] + rr[c] + rr[97+c] + bias[c] + bias[97+c]);
        if (lane < 48)
            out[(size_t)n*97 + c + 1] = 0.5f*(A0y + s_a1[wv][c+1] + rr[c+1] + rr[98+c] + bias[c+1] + bias[98+c]);
    }
}

extern "C" void kernel_launch(void* const* d_in, const int* in_sizes, int n_in,
                              void* d_out, int out_size, void* d_ws, size_t ws_size,
                              hipStream_t stream)
{
    const float* x   = (const float*)d_in[0];
    const int*   esrc= (const int*)  d_in[1];
    const int*   edst= (const int*)  d_in[2];
    const float* W0  = (const float*)d_in[3];
    const float* al0 = (const float*)d_in[4];
    const float* ar0 = (const float*)d_in[5];
    const float* b0  = (const float*)d_in[6];
    const float* W1  = (const float*)d_in[7];
    const float* al1 = (const float*)d_in[8];
    const float* ar1 = (const float*)d_in[9];
    const float* b1  = (const float*)d_in[10];
    const float* W2  = (const float*)d_in[11];
    const float* al2 = (const float*)d_in[12];
    const float* ar2 = (const float*)d_in[13];
    const float* b2  = (const float*)d_in[14];
    const float* rW2 = (const float*)d_in[15];
    float* out = (float*)d_out;

    const int N = NNODES, E = NEDGES;
    float* ws = (float*)d_ws;
    size_t o = 0;
    auto alloc_f = [&](size_t count) { float* p = ws + o; o += (count + 3) & ~(size_t)3; return p; };
    float* h1  = alloc_f((size_t)N * 128);
    float* rs2 = alloc_f((size_t)N * 194);
    float* el  = alloc_f((size_t)N * 2);
    float* er  = alloc_f((size_t)N * 2);
    uint*  ftb = (uint*)alloc_f((size_t)N * 97);
    u16* Xh  = (u16*)alloc_f((size_t)NPAD * 64);   // NPAD*128 ushorts
    u16* Xl  = (u16*)alloc_f((size_t)NPAD * 64);
    u16* H1h = (u16*)alloc_f((size_t)NPAD * 64);
    u16* H1l = (u16*)alloc_f((size_t)NPAD * 64);
    u16* B0h = (u16*)alloc_f(128*64); u16* B0l = (u16*)alloc_f(128*64);
    u16* B1h = (u16*)alloc_f(128*64); u16* B1l = (u16*)alloc_f(128*64);
    u16* B2h = (u16*)alloc_f(256*64); u16* B2l = (u16*)alloc_f(256*64);
    u16* Brh = (u16*)alloc_f(256*64); u16* Brl = (u16*)alloc_f(256*64);
    int* row_start = (int*)alloc_f(N + 4);
    int* cursor    = (int*)alloc_f(N);
    int* ssorted   = (int*)alloc_f(E);

    // ---- CSR by dst ----
    hipMemsetAsync(cursor, 0, N * sizeof(int), stream);
    hist_kernel<<<(E + 255) / 256, 256, 0, stream>>>(edst, cursor, E);
    scan_kernel<<<1, 1024, 0, stream>>>(cursor, row_start, N);
    hipMemsetAsync(cursor, 0, N * sizeof(int), stream);
    scatter_kernel<<<(E + 255) / 256, 256, 0, stream>>>(esrc, edst, row_start, cursor, ssorted, E);

    // ---- pre-split inputs ----
    split_x<<<NPAD * 32 / 256, 256, 0, stream>>>(x, Xh, Xl, N);
    split_w<<<(128*128 + 255)/256, 256, 0, stream>>>(W0,  B0h, B0l, 128, 128);
    split_w<<<(128*128 + 255)/256, 256, 0, stream>>>(W1,  B1h, B1l, 128, 128);
    split_w<<<(256*128 + 255)/256, 256, 0, stream>>>(W2,  B2h, B2l, 194, 256);
    split_w<<<(256*128 + 255)/256, 256, 0, stream>>>(rW2, Brh, Brl, 194, 256);
    zero_pad2<<<24, 256, 0, stream>>>(H1h, H1l);

    const int gx = NPAD / 64;                    // 782
    dim3 g128(gx, 1), g194(gx, 2);
    const int agg_grid  = N / 4;                 // 12500
    const int elr_grid  = (N + 3) / 4;

    // ---- layer 0 ----
    gemm_mfma<true><<<g128, 256, 0, stream>>>(Xh, Xl, B0h, B0l, ftb, N, 128);
    compute_elr<128,64><<<elr_grid, 256, 0, stream>>>(ftb, al0, ar0, el, er, N);
    gat_agg128<0><<<agg_grid, 256, 0, stream>>>(ftb, el, er, row_start, ssorted, nullptr, b0, h1, H1h, H1l);

    // ---- layer 1 (identity residual) ----
    gemm_mfma<true><<<g128, 256, 0, stream>>>(H1h, H1l, B1h, B1l, ftb, N, 128);
    compute_elr<128,64><<<elr_grid, 256, 0, stream>>>(ftb, al1, ar1, el, er, N);
    gat_agg128<1><<<agg_grid, 256, 0, stream>>>(ftb, el, er, row_start, ssorted, h1, b1, nullptr, Xh, Xl);  // h2 split -> Xh/Xl (x no longer needed; pads still zero)

    // ---- output layer ----
    gemm_mfma<true ><<<g194, 256, 0, stream>>>(Xh, Xl, B2h, B2l, ftb, N, 194);
    gemm_mfma<false><<<g194, 256, 0, stream>>>(Xh, Xl, Brh, Brl, rs2, N, 194);
    compute_elr<194,97><<<elr_grid, 256, 0, stream>>>(ftb, al2, ar2, el, er, N);
    gat_agg_out<<<agg_grid, 256, 0, stream>>>(ftb, el, er, row_start, ssorted, rs2, b2, out);
}

// Round 4
// 408.446 us; speedup vs baseline: 1.1330x; 1.1330x over previous
//
#include <hip/hip_runtime.h>
#include <math.h>

#define NNODES 50000
#define NEDGES 800000
#define NPAD   50048   // 782 * 64

typedef unsigned int uint;
typedef unsigned short u16;
typedef __bf16 bf16x8 __attribute__((ext_vector_type(8)));
typedef float f32x4 __attribute__((ext_vector_type(4)));

__device__ __forceinline__ float lrelu(float x){ return x > 0.f ? x : 0.2f*x; }
__device__ __forceinline__ float elu_f(float x){ return x > 0.f ? x : expm1f(x); }
__device__ __forceinline__ u16 f2bf(float f){
    uint u = __float_as_uint(f);
    return (u16)((u + 0x7fffu + ((u >> 16) & 1u)) >> 16);
}
__device__ __forceinline__ float bf2f(u16 h){ return __uint_as_float(((uint)h) << 16); }
__device__ __forceinline__ float blo(uint u){ return __uint_as_float(u << 16); }
__device__ __forceinline__ float bhi(uint u){ return __uint_as_float(u & 0xffff0000u); }

// ================= input splitting =================
__global__ void split_x(const float* __restrict__ x, u16* __restrict__ Xh, u16* __restrict__ Xl, int N)
{
    int idx = blockIdx.x * blockDim.x + threadIdx.x;       // one float4 per thread
    if (idx >= NPAD * 32) return;
    int n = idx >> 5;
    float4 v = make_float4(0.f, 0.f, 0.f, 0.f);
    if (n < N) v = ((const float4*)x)[idx];
    ushort4 h, l;
    h.x = f2bf(v.x); l.x = f2bf(v.x - bf2f(h.x));
    h.y = f2bf(v.y); l.y = f2bf(v.y - bf2f(h.y));
    h.z = f2bf(v.z); l.z = f2bf(v.z - bf2f(h.z));
    h.w = f2bf(v.w); l.w = f2bf(v.w - bf2f(h.w));
    ((ushort4*)Xh)[idx] = h;
    ((ushort4*)Xl)[idx] = l;
}

// W [128][Cc] f32 -> hi/lo ushort [CP][128] (transposed, col-padded with zeros)
__global__ void split_w(const float* __restrict__ W, u16* __restrict__ Bh, u16* __restrict__ Bl, int Cc, int CP)
{
    int idx = blockIdx.x * blockDim.x + threadIdx.x;       // idx = col*128 + k
    if (idx >= CP * 128) return;
    int col = idx >> 7, k = idx & 127;
    float v = (col < Cc) ? W[k * Cc + col] : 0.f;
    u16 h = f2bf(v);
    Bh[idx] = h;
    Bl[idx] = f2bf(v - bf2f(h));
}

__global__ void zero_pad2(u16* __restrict__ Hh, u16* __restrict__ Hl)
{
    int idx = blockIdx.x * blockDim.x + threadIdx.x;       // (NPAD-NNODES)*128 = 6144
    if (idx < (NPAD - NNODES) * 128) {
        Hh[(size_t)NNODES * 128 + idx] = 0;
        Hl[(size_t)NNODES * 128 + idx] = 0;
    }
}

// ================= GEMM: B staged in LDS (padded), A in registers =================
// BM=64 (4 waves x 16 rows), BN=128, K=128 in two 64-halves.
// grid.y==1: single matrix (B2 args), bf16 out. grid.y==4: y<2 -> B2 -> obf (bf16),
// y>=2 -> Br -> of32 (f32); coloff = (y&1)*128.
__global__ __launch_bounds__(256)
void gemm_blds(const u16* __restrict__ Ah, const u16* __restrict__ Al,
               const u16* __restrict__ B2h, const u16* __restrict__ B2l,
               const u16* __restrict__ Brh, const u16* __restrict__ Brl,
               u16* __restrict__ obf, float* __restrict__ of32, int N, int Cc)
{
    __shared__ u16 sBh[128][72];
    __shared__ u16 sBl[128][72];
    const int y = blockIdx.y;
    const bool second = (gridDim.y == 4) && (y >= 2);
    const bool outbf  = !second;
    const int coloff  = (gridDim.y == 4) ? (y & 1) * 128 : 0;
    const u16* __restrict__ Bh = second ? Brh : B2h;
    const u16* __restrict__ Bl = second ? Brl : B2l;

    const int bm = blockIdx.x * 64;
    const int tid = threadIdx.x, wid = tid >> 6, lane = tid & 63;
    const int lr = lane & 15, lk8 = (lane >> 4) << 3;

    // A fragments upfront: row = bm + wid*16 + lr, k = kt*32 + lk8 + (0..7)
    bf16x8 aH[4], aL[4];
    {
        size_t abase = (size_t)(bm + wid*16 + lr) * 128 + lk8;
        #pragma unroll
        for (int kt = 0; kt < 4; kt++) {
            aH[kt] = *(const bf16x8*)(Ah + abase + kt*32);
            aL[kt] = *(const bf16x8*)(Al + abase + kt*32);
        }
    }
    f32x4 acc[8] = {};

    const int scol = tid >> 1, sseg = (tid & 1) * 32;      // staging: 32 u16 per thread
    #pragma unroll
    for (int half = 0; half < 2; half++) {
        if (half) __syncthreads();
        {
            const u16* gh = Bh + (size_t)(coloff + scol) * 128 + half*64 + sseg;
            const u16* gl = Bl + (size_t)(coloff + scol) * 128 + half*64 + sseg;
            #pragma unroll
            for (int j = 0; j < 4; j++) {
                *(uint4*)&sBh[scol][sseg + j*8] = *(const uint4*)(gh + j*8);
                *(uint4*)&sBl[scol][sseg + j*8] = *(const uint4*)(gl + j*8);
            }
        }
        __syncthreads();
        #pragma unroll
        for (int ks = 0; ks < 2; ks++) {
            const int kt = half*2 + ks;
            #pragma unroll
            for (int fs = 0; fs < 8; fs++) {
                bf16x8 bH = *(const bf16x8*)&sBh[fs*16 + lr][ks*32 + lk8];
                bf16x8 bL = *(const bf16x8*)&sBl[fs*16 + lr][ks*32 + lk8];
                acc[fs] = __builtin_amdgcn_mfma_f32_16x16x32_bf16(aH[kt], bH, acc[fs], 0, 0, 0);
                acc[fs] = __builtin_amdgcn_mfma_f32_16x16x32_bf16(aH[kt], bL, acc[fs], 0, 0, 0);
                acc[fs] = __builtin_amdgcn_mfma_f32_16x16x32_bf16(aL[kt], bH, acc[fs], 0, 0, 0);
            }
        }
    }
    // D mapping: col = lane&15, row = (lane>>4)*4 + v
    #pragma unroll
    for (int fs = 0; fs < 8; fs++) {
        int col = coloff + fs*16 + lr;
        if (col >= Cc) continue;
        #pragma unroll
        for (int v = 0; v < 4; v++) {
            int row = bm + wid*16 + ((lane >> 4) << 2) + v;
            if (row < N) {
                if (outbf) obf[(size_t)row * Cc + col] = f2bf(acc[fs][v]);
                else       of32[(size_t)row * Cc + col] = acc[fs][v];
            }
        }
    }
}

// ================= el/er from bf16 ft =================
template<int C, int D>
__global__ void compute_elr(const uint* __restrict__ ftb, const float* __restrict__ al,
                            const float* __restrict__ ar, float* __restrict__ el,
                            float* __restrict__ er, int N)
{
    int wv = threadIdx.x >> 6, lane = threadIdx.x & 63;
    int n = blockIdx.x * 4 + wv;
    if (n >= N) return;
    const uint* row = ftb + (size_t)n * (C/2);
    float l0=0.f, l1=0.f, r0=0.f, r1=0.f;
    for (int p = lane; p < C/2; p += 64) {
        uint u = row[p];
        float f0 = blo(u), f1 = bhi(u);
        int c0 = 2*p, c1 = 2*p + 1;
        float a0 = al[c0], a1 = al[c1], g0 = ar[c0], g1 = ar[c1];
        if (c0 < D) { l0 += f0*a0; r0 += f0*g0; } else { l1 += f0*a0; r1 += f0*g0; }
        if (c1 < D) { l0 += f1*a1; r0 += f1*g1; } else { l1 += f1*a1; r1 += f1*g1; }
    }
    #pragma unroll
    for (int off = 32; off; off >>= 1) {
        l0 += __shfl_down(l0, off); l1 += __shfl_down(l1, off);
        r0 += __shfl_down(r0, off); r1 += __shfl_down(r1, off);
    }
    if (lane == 0) { el[2*n] = l0; el[2*n+1] = l1; er[2*n] = r0; er[2*n+1] = r1; }
}

// ================= CSR build (parallel decoupled scan) =================
__global__ void hist_kernel(const int* __restrict__ dst, int* __restrict__ counts, int E)
{
    int i = blockIdx.x * blockDim.x + threadIdx.x;
    if (i < E) atomicAdd(&counts[dst[i]], 1);
}

// block b: local inclusive scan of counts[b*4096 .. +4096) -> row_start[i+1]; partials[b] = tile sum
__global__ __launch_bounds__(1024)
void scan_local(const int* __restrict__ counts, int* __restrict__ row_start,
                int* __restrict__ partials, int n)
{
    __shared__ int wsum[16];
    const int tid = threadIdx.x, lane = tid & 63, wv = tid >> 6;
    const int i0 = blockIdx.x * 4096 + tid * 4;
    int v[4];
    #pragma unroll
    for (int j = 0; j < 4; j++) { int i = i0 + j; v[j] = (i < n) ? counts[i] : 0; }
    v[1] += v[0]; v[2] += v[1]; v[3] += v[2];
    int t = v[3];
    #pragma unroll
    for (int off = 1; off < 64; off <<= 1) {
        int u = __shfl_up(t, off);
        if (lane >= off) t += u;
    }
    int texcl = t - v[3];
    if (lane == 63) wsum[wv] = t;
    __syncthreads();
    int woff = 0;
    for (int w = 0; w < 16; w++) if (w < wv) woff += wsum[w];
    #pragma unroll
    for (int j = 0; j < 4; j++) { int i = i0 + j; if (i < n) row_start[i+1] = woff + texcl + v[j]; }
    if (tid == 0) {
        int tot = 0;
        for (int w = 0; w < 16; w++) tot += wsum[w];
        partials[blockIdx.x] = tot;
    }
}

__global__ void scan_offs(int* __restrict__ partials, int nb)
{
    int lane = threadIdx.x;
    int v = (lane < nb) ? partials[lane] : 0;
    int t = v;
    #pragma unroll
    for (int off = 1; off < 64; off <<= 1) {
        int u = __shfl_up(t, off);
        if (lane >= off) t += u;
    }
    if (lane < nb) partials[lane] = t - v;   // exclusive
}

__global__ __launch_bounds__(1024)
void scan_add(int* __restrict__ row_start, const int* __restrict__ partials, int n)
{
    const int tid = threadIdx.x;
    const int add = partials[blockIdx.x];
    const int i0 = blockIdx.x * 4096 + tid * 4;
    #pragma unroll
    for (int j = 0; j < 4; j++) { int i = i0 + j; if (i < n) row_start[i+1] += add; }
    if (blockIdx.x == 0 && tid == 0) row_start[0] = 0;
}

__global__ void scatter_kernel(const int* __restrict__ src, const int* __restrict__ dst,
                               const int* __restrict__ row_start, int* __restrict__ cursor,
                               int* __restrict__ src_sorted, int E)
{
    int i = blockIdx.x * blockDim.x + threadIdx.x;
    if (i < E) {
        int d = dst[i];
        int p = atomicAdd(&cursor[d], 1);
        src_sorted[row_start[d] + p] = src[i];
    }
}

// ================= aggregation, C=128 layers: one wave per dst node =================
// MODE 0: no res. MODE 1: residual reconstructed from Rh+Rl. Writes bf16 hi/lo split only.
template<int MODE>
__global__ __launch_bounds__(256)
void gat_agg128(const uint* __restrict__ ftb, const float* __restrict__ el,
                const float* __restrict__ er, const int* __restrict__ row_start,
                const int* __restrict__ ssorted, const u16* __restrict__ Rh,
                const u16* __restrict__ Rl, const float* __restrict__ bias,
                u16* __restrict__ Hh, u16* __restrict__ Hl)
{
    __shared__ int   s_src[4][64];
    __shared__ float s_w[4][2][64];
    const int wv = threadIdx.x >> 6, lane = threadIdx.x & 63;
    const int n = blockIdx.x * 4 + wv;
    const int beg = row_start[n];
    const int deg = row_start[n+1] - beg;
    const float2 ern = *(const float2*)(er + 2*(size_t)n);
    const int h = lane >> 5;
    float ax = 0.f, ay = 0.f, dp0 = 0.f, dp1 = 0.f;

    for (int cb = 0; cb < deg; cb += 64) {
        const int cnt = min(64, deg - cb);
        float w0 = 0.f, w1 = 0.f; int s = 0;
        if (lane < cnt) {
            s = ssorted[beg + cb + lane];
            float2 e = *(const float2*)(el + 2*(size_t)s);
            w0 = __expf(lrelu(e.x + ern.x));     // no max subtraction: |logit| small
            w1 = __expf(lrelu(e.y + ern.y));
        }
        dp0 += w0; dp1 += w1;
        s_src[wv][lane] = s; s_w[wv][0][lane] = w0; s_w[wv][1][lane] = w1;
        asm volatile("s_waitcnt lgkmcnt(0)" ::: "memory");   // wave-synchronous LDS publish
        int t = 0;
        for (; t + 4 <= cnt; t += 4) {
            int4   s4 = *(const int4*)&s_src[wv][t];
            float4 w4 = *(const float4*)&s_w[wv][h][t];
            uint u0 = ftb[((uint)s4.x << 6) + lane];
            uint u1 = ftb[((uint)s4.y << 6) + lane];
            uint u2 = ftb[((uint)s4.z << 6) + lane];
            uint u3 = ftb[((uint)s4.w << 6) + lane];
            ax += w4.x*blo(u0); ay += w4.x*bhi(u0);
            ax += w4.y*blo(u1); ay += w4.y*bhi(u1);
            ax += w4.z*blo(u2); ay += w4.z*bhi(u2);
            ax += w4.w*blo(u3); ay += w4.w*bhi(u3);
        }
        for (; t < cnt; t++) {
            int sv = s_src[wv][t];
            float w = s_w[wv][h][t];
            uint u = ftb[((uint)sv << 6) + lane];
            ax += w*blo(u); ay += w*bhi(u);
        }
    }
    #pragma unroll
    for (int off = 32; off; off >>= 1) { dp0 += __shfl_xor(dp0, off); dp1 += __shfl_xor(dp1, off); }
    const float den = (h == 0) ? dp0 : dp1;
    float r0 = (deg > 0) ? ax / den : 0.f;
    float r1 = (deg > 0) ? ay / den : 0.f;
    const int c0 = 2 * lane;
    const size_t ob = (size_t)n*128 + c0;
    const float2 bv = *(const float2*)(bias + c0);
    float v0 = r0 + bv.x, v1 = r1 + bv.y;
    if (MODE == 1) {
        ushort2 rh = *(const ushort2*)&Rh[ob];
        ushort2 rl = *(const ushort2*)&Rl[ob];
        v0 += bf2f(rh.x) + bf2f(rl.x);
        v1 += bf2f(rh.y) + bf2f(rl.y);
    }
    v0 = elu_f(v0); v1 = elu_f(v1);
    u16 h0 = f2bf(v0), h1v = f2bf(v1);
    *(ushort2*)&Hh[ob] = make_ushort2(h0, h1v);
    *(ushort2*)&Hl[ob] = make_ushort2(f2bf(v0 - bf2f(h0)), f2bf(v1 - bf2f(h1v)));
}

// ================= output-layer aggregation: one wave per dst node, C=194 D=97 =================
__global__ __launch_bounds__(256)
void gat_agg_out(const uint* __restrict__ ftb, const float* __restrict__ el,
                 const float* __restrict__ er, const int* __restrict__ row_start,
                 const int* __restrict__ ssorted, const float* __restrict__ res,
                 const float* __restrict__ bias, float* __restrict__ out)
{
    __shared__ int   s_src[4][64];
    __shared__ float s_w[4][2][64];
    __shared__ float s_a1[4][97];
    const int wv = threadIdx.x >> 6, lane = threadIdx.x & 63;
    const int n = blockIdx.x * 4 + wv;
    if (n >= NNODES - 1) return;                 // wave-uniform exit, no barriers used
    const int beg = row_start[n];
    const int deg = row_start[n+1] - beg;
    const float2 ern = *(const float2*)(er + 2*(size_t)n);
    const bool dual = (lane < 33);
    const bool xh0 = (lane <= 48), yh0 = (lane <= 47);
    float ax1=0.f, ay1=0.f, ax2=0.f, ay2=0.f, dp0=0.f, dp1=0.f;

    for (int cb = 0; cb < deg; cb += 64) {
        const int cnt = min(64, deg - cb);
        float w0 = 0.f, w1 = 0.f; int s = 0;
        if (lane < cnt) {
            s = ssorted[beg + cb + lane];
            float2 e = *(const float2*)(el + 2*(size_t)s);
            w0 = __expf(lrelu(e.x + ern.x));
            w1 = __expf(lrelu(e.y + ern.y));
        }
        dp0 += w0; dp1 += w1;
        s_src[wv][lane] = s; s_w[wv][0][lane] = w0; s_w[wv][1][lane] = w1;
        asm volatile("s_waitcnt lgkmcnt(0)" ::: "memory");
        int t = 0;
        for (; t + 4 <= cnt; t += 4) {
            int4   s4 = *(const int4*)&s_src[wv][t];
            float4 q0 = *(const float4*)&s_w[wv][0][t];
            float4 q1 = *(const float4*)&s_w[wv][1][t];
            #pragma unroll
            for (int j = 0; j < 4; j++) {
                int sv = (j==0) ? s4.x : (j==1) ? s4.y : (j==2) ? s4.z : s4.w;
                float f0 = (j==0) ? q0.x : (j==1) ? q0.y : (j==2) ? q0.z : q0.w;
                float f1 = (j==0) ? q1.x : (j==1) ? q1.y : (j==2) ? q1.z : q1.w;
                const uint* row = ftb + (uint)sv * 97u;
                uint u1 = row[lane];
                uint u2 = dual ? row[64 + lane] : 0u;
                float wx = xh0 ? f0 : f1, wy = yh0 ? f0 : f1;
                ax1 += wx*blo(u1); ay1 += wy*bhi(u1);
                ax2 += f1*blo(u2); ay2 += f1*bhi(u2);
            }
        }
        for (; t < cnt; t++) {
            int sv = s_src[wv][t];
            float f0 = s_w[wv][0][t], f1 = s_w[wv][1][t];
            const uint* row = ftb + (uint)sv * 97u;
            uint u1 = row[lane];
            uint u2 = dual ? row[64 + lane] : 0u;
            float wx = xh0 ? f0 : f1, wy = yh0 ? f0 : f1;
            ax1 += wx*blo(u1); ay1 += wy*bhi(u1);
            ax2 += f1*blo(u2); ay2 += f1*bhi(u2);
        }
    }
    #pragma unroll
    for (int off = 32; off; off >>= 1) { dp0 += __shfl_xor(dp0, off); dp1 += __shfl_xor(dp1, off); }
    const float i0 = (deg > 0) ? 1.f/dp0 : 0.f;
    const float i1 = (deg > 0) ? 1.f/dp1 : 0.f;
    float A0x = ax1 * (xh0 ? i0 : i1);
    float A0y = ay1 * (yh0 ? i0 : i1);
    float A2x = ax2 * i1, A2y = ay2 * i1;
    if (lane == 48)      s_a1[wv][0] = A0y;
    else if (lane >= 49) { s_a1[wv][2*lane - 97] = A0x; s_a1[wv][2*lane - 96] = A0y; }
    if (dual)            { s_a1[wv][31 + 2*lane] = A2x; s_a1[wv][32 + 2*lane] = A2y; }
    asm volatile("s_waitcnt lgkmcnt(0)" ::: "memory");
    if (lane <= 48) {
        const int c = 2 * lane;
        const float* rr = res + (size_t)n * 194;
        out[(size_t)n*97 + c] = 0.5f*(A0x + s_a1[wv][c] + rr[c] + rr[97+c] + bias[c] + bias[97+c]);
        if (lane < 48)
            out[(size_t)n*97 + c + 1] = 0.5f*(A0y + s_a1[wv][c+1] + rr[c+1] + rr[98+c] + bias[c+1] + bias[98+c]);
    }
}

extern "C" void kernel_launch(void* const* d_in, const int* in_sizes, int n_in,
                              void* d_out, int out_size, void* d_ws, size_t ws_size,
                              hipStream_t stream)
{
    const float* x   = (const float*)d_in[0];
    const int*   esrc= (const int*)  d_in[1];
    const int*   edst= (const int*)  d_in[2];
    const float* W0  = (const float*)d_in[3];
    const float* al0 = (const float*)d_in[4];
    const float* ar0 = (const float*)d_in[5];
    const float* b0  = (const float*)d_in[6];
    const float* W1  = (const float*)d_in[7];
    const float* al1 = (const float*)d_in[8];
    const float* ar1 = (const float*)d_in[9];
    const float* b1  = (const float*)d_in[10];
    const float* W2  = (const float*)d_in[11];
    const float* al2 = (const float*)d_in[12];
    const float* ar2 = (const float*)d_in[13];
    const float* b2  = (const float*)d_in[14];
    const float* rW2 = (const float*)d_in[15];
    float* out = (float*)d_out;

    const int N = NNODES, E = NEDGES;
    const int NB = (N + 4095) / 4096;            // 13 scan tiles
    float* ws = (float*)d_ws;
    size_t o = 0;
    auto alloc_f = [&](size_t count) { float* p = ws + o; o += (count + 3) & ~(size_t)3; return p; };
    float* rs2 = alloc_f((size_t)N * 194);
    float* el  = alloc_f((size_t)N * 2);
    float* er  = alloc_f((size_t)N * 2);
    uint*  ftb = (uint*)alloc_f((size_t)N * 97);
    u16* Xh  = (u16*)alloc_f((size_t)NPAD * 64);
    u16* Xl  = (u16*)alloc_f((size_t)NPAD * 64);
    u16* H1h = (u16*)alloc_f((size_t)NPAD * 64);
    u16* H1l = (u16*)alloc_f((size_t)NPAD * 64);
    u16* B0h = (u16*)alloc_f(128*64); u16* B0l = (u16*)alloc_f(128*64);
    u16* B1h = (u16*)alloc_f(128*64); u16* B1l = (u16*)alloc_f(128*64);
    u16* B2h = (u16*)alloc_f(256*64); u16* B2l = (u16*)alloc_f(256*64);
    u16* Brh = (u16*)alloc_f(256*64); u16* Brl = (u16*)alloc_f(256*64);
    int* row_start = (int*)alloc_f(N + 4);
    int* cursor    = (int*)alloc_f(N);
    int* partials  = (int*)alloc_f(64);
    int* ssorted   = (int*)alloc_f(E);

    // ---- CSR by dst ----
    hipMemsetAsync(cursor, 0, N * sizeof(int), stream);
    hist_kernel<<<(E + 255) / 256, 256, 0, stream>>>(edst, cursor, E);
    scan_local<<<NB, 1024, 0, stream>>>(cursor, row_start, partials, N);
    scan_offs<<<1, 64, 0, stream>>>(partials, NB);
    scan_add<<<NB, 1024, 0, stream>>>(row_start, partials, N);
    hipMemsetAsync(cursor, 0, N * sizeof(int), stream);
    scatter_kernel<<<(E + 255) / 256, 256, 0, stream>>>(esrc, edst, row_start, cursor, ssorted, E);

    // ---- pre-split inputs ----
    split_x<<<NPAD * 32 / 256, 256, 0, stream>>>(x, Xh, Xl, N);
    split_w<<<(128*128 + 255)/256, 256, 0, stream>>>(W0,  B0h, B0l, 128, 128);
    split_w<<<(128*128 + 255)/256, 256, 0, stream>>>(W1,  B1h, B1l, 128, 128);
    split_w<<<(256*128 + 255)/256, 256, 0, stream>>>(W2,  B2h, B2l, 194, 256);
    split_w<<<(256*128 + 255)/256, 256, 0, stream>>>(rW2, Brh, Brl, 194, 256);
    zero_pad2<<<24, 256, 0, stream>>>(H1h, H1l);

    const int gx = NPAD / 64;                    // 782
    const int agg_grid = N / 4;                  // 12500
    const int elr_grid = (N + 3) / 4;

    // ---- layer 0 ----
    gemm_blds<<<dim3(gx,1), 256, 0, stream>>>(Xh, Xl, B0h, B0l, B0h, B0l, (u16*)ftb, nullptr, N, 128);
    compute_elr<128,64><<<elr_grid, 256, 0, stream>>>(ftb, al0, ar0, el, er, N);
    gat_agg128<0><<<agg_grid, 256, 0, stream>>>(ftb, el, er, row_start, ssorted, nullptr, nullptr, b0, H1h, H1l);

    // ---- layer 1 (identity residual from H1h+H1l) ----
    gemm_blds<<<dim3(gx,1), 256, 0, stream>>>(H1h, H1l, B1h, B1l, B1h, B1l, (u16*)ftb, nullptr, N, 128);
    compute_elr<128,64><<<elr_grid, 256, 0, stream>>>(ftb, al1, ar1, el, er, N);
    gat_agg128<1><<<agg_grid, 256, 0, stream>>>(ftb, el, er, row_start, ssorted, H1h, H1l, b1, Xh, Xl);

    // ---- output layer: fused dual GEMM (W2 -> ftb bf16, rW2 -> rs2 f32) ----
    gemm_blds<<<dim3(gx,4), 256, 0, stream>>>(Xh, Xl, B2h, B2l, Brh, Brl, (u16*)ftb, rs2, N, 194);
    compute_elr<194,97><<<elr_grid, 256, 0, stream>>>(ftb, al2, ar2, el, er, N);
    gat_agg_out<<<agg_grid, 256, 0, stream>>>(ftb, el, er, row_start, ssorted, rs2, b2, out);
}

// Round 6
// 330.312 us; speedup vs baseline: 1.4010x; 1.2365x over previous
//
#include <hip/hip_runtime.h>
#include <math.h>

#define NNODES 50000
#define NEDGES 800000
#define NPAD   50048   // 782 * 64

typedef unsigned int uint;
typedef unsigned short u16;
typedef __bf16 bf16x8 __attribute__((ext_vector_type(8)));
typedef float f32x4 __attribute__((ext_vector_type(4)));

__device__ __forceinline__ float lrelu(float x){ return x > 0.f ? x : 0.2f*x; }
__device__ __forceinline__ float elu_f(float x){ return x > 0.f ? x : expm1f(x); }
__device__ __forceinline__ u16 f2bf(float f){
    uint u = __float_as_uint(f);
    return (u16)((u + 0x7fffu + ((u >> 16) & 1u)) >> 16);
}
__device__ __forceinline__ float bf2f(u16 h){ return __uint_as_float(((uint)h) << 16); }
__device__ __forceinline__ float blo(uint u){ return __uint_as_float(u << 16); }
__device__ __forceinline__ float bhi(uint u){ return __uint_as_float(u & 0xffff0000u); }

// ================= input splitting =================
__global__ void split_x(const float* __restrict__ x, u16* __restrict__ Xh, u16* __restrict__ Xl, int N)
{
    int idx = blockIdx.x * blockDim.x + threadIdx.x;       // one float4 per thread
    if (idx >= NPAD * 32) return;
    int n = idx >> 5;
    float4 v = make_float4(0.f, 0.f, 0.f, 0.f);
    if (n < N) v = ((const float4*)x)[idx];
    ushort4 h, l;
    h.x = f2bf(v.x); l.x = f2bf(v.x - bf2f(h.x));
    h.y = f2bf(v.y); l.y = f2bf(v.y - bf2f(h.y));
    h.z = f2bf(v.z); l.z = f2bf(v.z - bf2f(h.z));
    h.w = f2bf(v.w); l.w = f2bf(v.w - bf2f(h.w));
    ((ushort4*)Xh)[idx] = h;
    ((ushort4*)Xl)[idx] = l;
}

// W [128][Cc] f32 -> Bh [CP][128] bf16 (transposed, col-padded with zeros), hi only
__global__ void split_w_hi(const float* __restrict__ W, u16* __restrict__ Bh, int Cc, int CP)
{
    int idx = blockIdx.x * blockDim.x + threadIdx.x;       // idx = col*128 + k
    if (idx >= CP * 128) return;
    int col = idx >> 7, k = idx & 127;
    float v = (col < Cc) ? W[k * Cc + col] : 0.f;
    Bh[idx] = f2bf(v);
}

__global__ void zero_pad2(u16* __restrict__ Hh, u16* __restrict__ Hl)
{
    int idx = blockIdx.x * blockDim.x + threadIdx.x;       // (NPAD-NNODES)*128 = 6144
    if (idx < (NPAD - NNODES) * 128) {
        Hh[(size_t)NNODES * 128 + idx] = 0;
        Hl[(size_t)NNODES * 128 + idx] = 0;
    }
}

// ================= GEMM layers 0/1: Cc=128, fused el/er epilogue =================
// BM=64 (4 waves x 16 rows), BN=128 (all cols), K=128 staged once. A hi/lo in regs, B hi in LDS.
__global__ __launch_bounds__(256, 4)
void gemm_l01(const u16* __restrict__ Ah, const u16* __restrict__ Al,
              const u16* __restrict__ Bh, u16* __restrict__ obf,
              const float* __restrict__ alv, const float* __restrict__ arv,
              float* __restrict__ el, float* __restrict__ er, int N)
{
    __shared__ u16 sB[128 * 136];
    const int bm = blockIdx.x * 64;
    const int tid = threadIdx.x, wid = tid >> 6, lane = tid & 63;
    const int lr = lane & 15, q = lane >> 4, lk8 = q << 3;

    // A fragments (issued first; latency hides under B staging + barrier)
    bf16x8 aH[4], aL[4];
    {
        size_t abase = (size_t)(bm + wid*16 + lr) * 128 + lk8;
        #pragma unroll
        for (int kt = 0; kt < 4; kt++) {
            aH[kt] = *(const bf16x8*)(Ah + abase + kt*32);
            aL[kt] = *(const bf16x8*)(Al + abase + kt*32);
        }
    }
    // stage B hi: 128 cols x 128 k; 64 u16 per thread = 8 x uint4 (8 u16 each)
    {
        const int c = tid >> 1, seg = (tid & 1) * 64;
        const u16* g = Bh + (size_t)c * 128 + seg;
        u16* s = sB + c * 136 + seg;
        #pragma unroll
        for (int j = 0; j < 8; j++)
            *(uint4*)(s + j*8) = *(const uint4*)(g + j*8);
    }
    __syncthreads();

    f32x4 acc[8];
    #pragma unroll
    for (int i = 0; i < 8; i++) acc[i] = (f32x4){0.f,0.f,0.f,0.f};

    #pragma unroll
    for (int kt = 0; kt < 4; kt++)
        #pragma unroll
        for (int fs = 0; fs < 8; fs++) {
            bf16x8 b = *(const bf16x8*)(sB + (fs*16 + lr)*136 + kt*32 + lk8);
            acc[fs] = __builtin_amdgcn_mfma_f32_16x16x32_bf16(aH[kt], b, acc[fs], 0, 0, 0);
            acc[fs] = __builtin_amdgcn_mfma_f32_16x16x32_bf16(aL[kt], b, acc[fs], 0, 0, 0);
        }

    // epilogue: bf16 store + fused el/er (head0 = fs<4, head1 = fs>=4)
    float el0[4] = {0,0,0,0}, el1[4] = {0,0,0,0}, er0[4] = {0,0,0,0}, er1[4] = {0,0,0,0};
    #pragma unroll
    for (int fs = 0; fs < 8; fs++) {
        const int col = fs*16 + lr;
        const float av = alv[col], gv = arv[col];
        #pragma unroll
        for (int v = 0; v < 4; v++) {
            float f = acc[fs][v];
            int row = bm + wid*16 + q*4 + v;
            if (row < N) obf[(size_t)row * 128 + col] = f2bf(f);
            if (fs < 4) { el0[v] += f * av; er0[v] += f * gv; }
            else        { el1[v] += f * av; er1[v] += f * gv; }
        }
    }
    #pragma unroll
    for (int off = 1; off < 16; off <<= 1) {
        #pragma unroll
        for (int v = 0; v < 4; v++) {
            el0[v] += __shfl_xor(el0[v], off);
            el1[v] += __shfl_xor(el1[v], off);
            er0[v] += __shfl_xor(er0[v], off);
            er1[v] += __shfl_xor(er1[v], off);
        }
    }
    if (lr == 0) {
        #pragma unroll
        for (int v = 0; v < 4; v++) {
            int row = bm + wid*16 + q*4 + v;
            if (row < N) {
                *(float2*)(el + 2*(size_t)row) = make_float2(el0[v], el1[v]);
                *(float2*)(er + 2*(size_t)row) = make_float2(er0[v], er1[v]);
            }
        }
    }
}

// ================= GEMM layer 2: dual-matrix, 2 col-tiles, XCD-coscheduled =================
// bid decode: x = (bid>>5)*8 + (bid&7), sel = (bid>>3)&3. Jobs sharing an A-tile have
// bid = base + sel*8 -> identical (mod 8) -> same XCD L2.
__global__ __launch_bounds__(256, 4)
void gemm_l2(const u16* __restrict__ Ah, const u16* __restrict__ Al,
             const u16* __restrict__ B2, const u16* __restrict__ Br,
             u16* __restrict__ obf, float* __restrict__ of32, int N)
{
    __shared__ u16 sB[128 * 136];
    const int bid = blockIdx.x;
    const int x = (bid >> 5) * 8 + (bid & 7);
    const int sel = (bid >> 3) & 3;
    if (x >= NPAD / 64) return;                 // block-uniform
    const bool second = (sel >= 2);             // rW2 -> f32 rs2
    const int coloff = (sel & 1) * 128;
    const u16* __restrict__ B = second ? Br : B2;

    const int bm = x * 64;
    const int tid = threadIdx.x, wid = tid >> 6, lane = tid & 63;
    const int lr = lane & 15, q = lane >> 4, lk8 = q << 3;

    bf16x8 aH[4], aL[4];
    {
        size_t abase = (size_t)(bm + wid*16 + lr) * 128 + lk8;
        #pragma unroll
        for (int kt = 0; kt < 4; kt++) {
            aH[kt] = *(const bf16x8*)(Ah + abase + kt*32);
            aL[kt] = *(const bf16x8*)(Al + abase + kt*32);
        }
    }
    {
        const int c = tid >> 1, seg = (tid & 1) * 64;
        const u16* g = B + (size_t)(coloff + c) * 128 + seg;
        u16* s = sB + c * 136 + seg;
        #pragma unroll
        for (int j = 0; j < 8; j++)
            *(uint4*)(s + j*8) = *(const uint4*)(g + j*8);
    }
    __syncthreads();

    f32x4 acc[8];
    #pragma unroll
    for (int i = 0; i < 8; i++) acc[i] = (f32x4){0.f,0.f,0.f,0.f};

    #pragma unroll
    for (int kt = 0; kt < 4; kt++)
        #pragma unroll
        for (int fs = 0; fs < 8; fs++) {
            bf16x8 b = *(const bf16x8*)(sB + (fs*16 + lr)*136 + kt*32 + lk8);
            acc[fs] = __builtin_amdgcn_mfma_f32_16x16x32_bf16(aH[kt], b, acc[fs], 0, 0, 0);
            acc[fs] = __builtin_amdgcn_mfma_f32_16x16x32_bf16(aL[kt], b, acc[fs], 0, 0, 0);
        }

    #pragma unroll
    for (int fs = 0; fs < 8; fs++) {
        const int col = coloff + fs*16 + lr;
        if (col >= 194) continue;
        #pragma unroll
        for (int v = 0; v < 4; v++) {
            int row = bm + wid*16 + q*4 + v;
            if (row < N) {
                if (second) of32[(size_t)row * 194 + col] = acc[fs][v];
                else        obf[(size_t)row * 194 + col] = f2bf(acc[fs][v]);
            }
        }
    }
}

// ================= el/er for layer 2 (C=194, D=97) =================
template<int C, int D>
__global__ void compute_elr(const uint* __restrict__ ftb, const float* __restrict__ al,
                            const float* __restrict__ ar, float* __restrict__ el,
                            float* __restrict__ er, int N)
{
    int wv = threadIdx.x >> 6, lane = threadIdx.x & 63;
    int n = blockIdx.x * 4 + wv;
    if (n >= N) return;
    const uint* row = ftb + (size_t)n * (C/2);
    float l0=0.f, l1=0.f, r0=0.f, r1=0.f;
    for (int p = lane; p < C/2; p += 64) {
        uint u = row[p];
        float f0 = blo(u), f1 = bhi(u);
        int c0 = 2*p, c1 = 2*p + 1;
        float a0 = al[c0], a1 = al[c1], g0 = ar[c0], g1 = ar[c1];
        if (c0 < D) { l0 += f0*a0; r0 += f0*g0; } else { l1 += f0*a0; r1 += f0*g0; }
        if (c1 < D) { l0 += f1*a1; r0 += f1*g1; } else { l1 += f1*a1; r1 += f1*g1; }
    }
    #pragma unroll
    for (int off = 32; off; off >>= 1) {
        l0 += __shfl_down(l0, off); l1 += __shfl_down(l1, off);
        r0 += __shfl_down(r0, off); r1 += __shfl_down(r1, off);
    }
    if (lane == 0) { el[2*n] = l0; el[2*n+1] = l1; er[2*n] = r0; er[2*n+1] = r1; }
}

// ================= CSR build (parallel decoupled scan) =================
__global__ void hist_kernel(const int* __restrict__ dst, int* __restrict__ counts, int E)
{
    int i = blockIdx.x * blockDim.x + threadIdx.x;
    if (i < E) atomicAdd(&counts[dst[i]], 1);
}

__global__ __launch_bounds__(1024)
void scan_local(const int* __restrict__ counts, int* __restrict__ row_start,
                int* __restrict__ partials, int n)
{
    __shared__ int wsum[16];
    const int tid = threadIdx.x, lane = tid & 63, wv = tid >> 6;
    const int i0 = blockIdx.x * 4096 + tid * 4;
    int v[4];
    #pragma unroll
    for (int j = 0; j < 4; j++) { int i = i0 + j; v[j] = (i < n) ? counts[i] : 0; }
    v[1] += v[0]; v[2] += v[1]; v[3] += v[2];
    int t = v[3];
    #pragma unroll
    for (int off = 1; off < 64; off <<= 1) {
        int u = __shfl_up(t, off);
        if (lane >= off) t += u;
    }
    int texcl = t - v[3];
    if (lane == 63) wsum[wv] = t;
    __syncthreads();
    int woff = 0;
    for (int w = 0; w < 16; w++) if (w < wv) woff += wsum[w];
    #pragma unroll
    for (int j = 0; j < 4; j++) { int i = i0 + j; if (i < n) row_start[i+1] = woff + texcl + v[j]; }
    if (tid == 0) {
        int tot = 0;
        for (int w = 0; w < 16; w++) tot += wsum[w];
        partials[blockIdx.x] = tot;
    }
}

__global__ void scan_offs(int* __restrict__ partials, int nb)
{
    int lane = threadIdx.x;
    int v = (lane < nb) ? partials[lane] : 0;
    int t = v;
    #pragma unroll
    for (int off = 1; off < 64; off <<= 1) {
        int u = __shfl_up(t, off);
        if (lane >= off) t += u;
    }
    if (lane < nb) partials[lane] = t - v;   // exclusive
}

__global__ __launch_bounds__(1024)
void scan_add(int* __restrict__ row_start, const int* __restrict__ partials, int n)
{
    const int tid = threadIdx.x;
    const int add = partials[blockIdx.x];
    const int i0 = blockIdx.x * 4096 + tid * 4;
    #pragma unroll
    for (int j = 0; j < 4; j++) { int i = i0 + j; if (i < n) row_start[i+1] += add; }
    if (blockIdx.x == 0 && tid == 0) row_start[0] = 0;
}

__global__ void scatter_kernel(const int* __restrict__ src, const int* __restrict__ dst,
                               const int* __restrict__ row_start, int* __restrict__ cursor,
                               int* __restrict__ src_sorted, int E)
{
    int i = blockIdx.x * blockDim.x + threadIdx.x;
    if (i < E) {
        int d = dst[i];
        int p = atomicAdd(&cursor[d], 1);
        src_sorted[row_start[d] + p] = src[i];
    }
}

// ================= aggregation, C=128 layers: one wave per dst node =================
template<int MODE>
__global__ __launch_bounds__(256)
void gat_agg128(const uint* __restrict__ ftb, const float* __restrict__ el,
                const float* __restrict__ er, const int* __restrict__ row_start,
                const int* __restrict__ ssorted, const u16* __restrict__ Rh,
                const u16* __restrict__ Rl, const float* __restrict__ bias,
                u16* __restrict__ Hh, u16* __restrict__ Hl)
{
    __shared__ int   s_src[4][64];
    __shared__ float s_w[4][2][64];
    const int wv = threadIdx.x >> 6, lane = threadIdx.x & 63;
    const int n = blockIdx.x * 4 + wv;
    const int beg = row_start[n];
    const int deg = row_start[n+1] - beg;
    const float2 ern = *(const float2*)(er + 2*(size_t)n);
    const int h = lane >> 5;
    float ax = 0.f, ay = 0.f, dp0 = 0.f, dp1 = 0.f;

    for (int cb = 0; cb < deg; cb += 64) {
        const int cnt = min(64, deg - cb);
        float w0 = 0.f, w1 = 0.f; int s = 0;
        if (lane < cnt) {
            s = ssorted[beg + cb + lane];
            float2 e = *(const float2*)(el + 2*(size_t)s);
            w0 = __expf(lrelu(e.x + ern.x));     // no max subtraction: |logit| small
            w1 = __expf(lrelu(e.y + ern.y));
        }
        dp0 += w0; dp1 += w1;
        s_src[wv][lane] = s; s_w[wv][0][lane] = w0; s_w[wv][1][lane] = w1;
        asm volatile("s_waitcnt lgkmcnt(0)" ::: "memory");   // wave-synchronous LDS publish
        int t = 0;
        for (; t + 4 <= cnt; t += 4) {
            int4   s4 = *(const int4*)&s_src[wv][t];
            float4 w4 = *(const float4*)&s_w[wv][h][t];
            uint u0 = ftb[((uint)s4.x << 6) + lane];
            uint u1 = ftb[((uint)s4.y << 6) + lane];
            uint u2 = ftb[((uint)s4.z << 6) + lane];
            uint u3 = ftb[((uint)s4.w << 6) + lane];
            ax += w4.x*blo(u0); ay += w4.x*bhi(u0);
            ax += w4.y*blo(u1); ay += w4.y*bhi(u1);
            ax += w4.z*blo(u2); ay += w4.z*bhi(u2);
            ax += w4.w*blo(u3); ay += w4.w*bhi(u3);
        }
        for (; t < cnt; t++) {
            int sv = s_src[wv][t];
            float w = s_w[wv][h][t];
            uint u = ftb[((uint)sv << 6) + lane];
            ax += w*blo(u); ay += w*bhi(u);
        }
    }
    #pragma unroll
    for (int off = 32; off; off >>= 1) { dp0 += __shfl_xor(dp0, off); dp1 += __shfl_xor(dp1, off); }
    const float den = (h == 0) ? dp0 : dp1;
    float r0 = (deg > 0) ? ax / den : 0.f;
    float r1 = (deg > 0) ? ay / den : 0.f;
    const int c0 = 2 * lane;
    const size_t ob = (size_t)n*128 + c0;
    const float2 bv = *(const float2*)(bias + c0);
    float v0 = r0 + bv.x, v1 = r1 + bv.y;
    if (MODE == 1) {
        ushort2 rh = *(const ushort2*)&Rh[ob];
        ushort2 rl = *(const ushort2*)&Rl[ob];
        v0 += bf2f(rh.x) + bf2f(rl.x);
        v1 += bf2f(rh.y) + bf2f(rl.y);
    }
    v0 = elu_f(v0); v1 = elu_f(v1);
    u16 h0 = f2bf(v0), h1v = f2bf(v1);
    *(ushort2*)&Hh[ob] = make_ushort2(h0, h1v);
    *(ushort2*)&Hl[ob] = make_ushort2(f2bf(v0 - bf2f(h0)), f2bf(v1 - bf2f(h1v)));
}

// ================= output-layer aggregation: one wave per dst node, C=194 D=97 =================
__global__ __launch_bounds__(256)
void gat_agg_out(const uint* __restrict__ ftb, const float* __restrict__ el,
                 const float* __restrict__ er, const int* __restrict__ row_start,
                 const int* __restrict__ ssorted, const float* __restrict__ res,
                 const float* __restrict__ bias, float* __restrict__ out)
{
    __shared__ int   s_src[4][64];
    __shared__ float s_w[4][2][64];
    __shared__ float s_a1[4][97];
    const int wv = threadIdx.x >> 6, lane = threadIdx.x & 63;
    const int n = blockIdx.x * 4 + wv;
    if (n >= NNODES - 1) return;                 // wave-uniform exit, no barriers used
    const int beg = row_start[n];
    const int deg = row_start[n+1] - beg;
    const float2 ern = *(const float2*)(er + 2*(size_t)n);
    const bool dual = (lane < 33);
    const bool xh0 = (lane <= 48), yh0 = (lane <= 47);
    float ax1=0.f, ay1=0.f, ax2=0.f, ay2=0.f, dp0=0.f, dp1=0.f;

    for (int cb = 0; cb < deg; cb += 64) {
        const int cnt = min(64, deg - cb);
        float w0 = 0.f, w1 = 0.f; int s = 0;
        if (lane < cnt) {
            s = ssorted[beg + cb + lane];
            float2 e = *(const float2*)(el + 2*(size_t)s);
            w0 = __expf(lrelu(e.x + ern.x));
            w1 = __expf(lrelu(e.y + ern.y));
        }
        dp0 += w0; dp1 += w1;
        s_src[wv][lane] = s; s_w[wv][0][lane] = w0; s_w[wv][1][lane] = w1;
        asm volatile("s_waitcnt lgkmcnt(0)" ::: "memory");
        int t = 0;
        for (; t + 4 <= cnt; t += 4) {
            int4   s4 = *(const int4*)&s_src[wv][t];
            float4 q0 = *(const float4*)&s_w[wv][0][t];
            float4 q1 = *(const float4*)&s_w[wv][1][t];
            #pragma unroll
            for (int j = 0; j < 4; j++) {
                int sv = (j==0) ? s4.x : (j==1) ? s4.y : (j==2) ? s4.z : s4.w;
                float f0 = (j==0) ? q0.x : (j==1) ? q0.y : (j==2) ? q0.z : q0.w;
                float f1 = (j==0) ? q1.x : (j==1) ? q1.y : (j==2) ? q1.z : q1.w;
                const uint* row = ftb + (uint)sv * 97u;
                uint u1 = row[lane];
                uint u2 = dual ? row[64 + lane] : 0u;
                float wx = xh0 ? f0 : f1, wy = yh0 ? f0 : f1;
                ax1 += wx*blo(u1); ay1 += wy*bhi(u1);
                ax2 += f1*blo(u2); ay2 += f1*bhi(u2);
            }
        }
        for (; t < cnt; t++) {
            int sv = s_src[wv][t];
            float f0 = s_w[wv][0][t], f1 = s_w[wv][1][t];
            const uint* row = ftb + (uint)sv * 97u;
            uint u1 = row[lane];
            uint u2 = dual ? row[64 + lane] : 0u;
            float wx = xh0 ? f0 : f1, wy = yh0 ? f0 : f1;
            ax1 += wx*blo(u1); ay1 += wy*bhi(u1);
            ax2 += f1*blo(u2); ay2 += f1*bhi(u2);
        }
    }
    #pragma unroll
    for (int off = 32; off; off >>= 1) { dp0 += __shfl_xor(dp0, off); dp1 += __shfl_xor(dp1, off); }
    const float i0 = (deg > 0) ? 1.f/dp0 : 0.f;
    const float i1 = (deg > 0) ? 1.f/dp1 : 0.f;
    float A0x = ax1 * (xh0 ? i0 : i1);
    float A0y = ay1 * (yh0 ? i0 : i1);
    float A2x = ax2 * i1, A2y = ay2 * i1;
    if (lane == 48)      s_a1[wv][0] = A0y;
    else if (lane >= 49) { s_a1[wv][2*lane - 97] = A0x; s_a1[wv][2*lane - 96] = A0y; }
    if (dual)            { s_a1[wv][31 + 2*lane] = A2x; s_a1[wv][32 + 2*lane] = A2y; }
    asm volatile("s_waitcnt lgkmcnt(0)" ::: "memory");
    if (lane <= 48) {
        const int c = 2 * lane;
        const float* rr = res + (size_t)n * 194;
        out[(size_t)n*97 + c] = 0.5f*(A0x + s_a1[wv][c] + rr[c] + rr[97+c] + bias[c] + bias[97+c]);
        if (lane < 48)
            out[(size_t)n*97 + c + 1] = 0.5f*(A0y + s_a1[wv][c+1] + rr[c+1] + rr[98+c] + bias[c+1] + bias[98+c]);
    }
}

extern "C" void kernel_launch(void* const* d_in, const int* in_sizes, int n_in,
                              void* d_out, int out_size, void* d_ws, size_t ws_size,
                              hipStream_t stream)
{
    const float* x   = (const float*)d_in[0];
    const int*   esrc= (const int*)  d_in[1];
    const int*   edst= (const int*)  d_in[2];
    const float* W0  = (const float*)d_in[3];
    const float* al0 = (const float*)d_in[4];
    const float* ar0 = (const float*)d_in[5];
    const float* b0  = (const float*)d_in[6];
    const float* W1  = (const float*)d_in[7];
    const float* al1 = (const float*)d_in[8];
    const float* ar1 = (const float*)d_in[9];
    const float* b1  = (const float*)d_in[10];
    const float* W2  = (const float*)d_in[11];
    const float* al2 = (const float*)d_in[12];
    const float* ar2 = (const float*)d_in[13];
    const float* b2  = (const float*)d_in[14];
    const float* rW2 = (const float*)d_in[15];
    float* out = (float*)d_out;

    const int N = NNODES, E = NEDGES;
    const int NB = (N + 4095) / 4096;            // 13 scan tiles
    float* ws = (float*)d_ws;
    size_t o = 0;
    auto alloc_f = [&](size_t count) { float* p = ws + o; o += (count + 3) & ~(size_t)3; return p; };
    float* rs2 = alloc_f((size_t)N * 194);
    float* el  = alloc_f((size_t)N * 2);
    float* er  = alloc_f((size_t)N * 2);
    uint*  ftb = (uint*)alloc_f((size_t)N * 97);
    u16* Xh  = (u16*)alloc_f((size_t)NPAD * 64);
    u16* Xl  = (u16*)alloc_f((size_t)NPAD * 64);
    u16* H1h = (u16*)alloc_f((size_t)NPAD * 64);
    u16* H1l = (u16*)alloc_f((size_t)NPAD * 64);
    u16* B0h = (u16*)alloc_f(128*64);
    u16* B1h = (u16*)alloc_f(128*64);
    u16* B2h = (u16*)alloc_f(256*64);
    u16* Brh = (u16*)alloc_f(256*64);
    int* row_start = (int*)alloc_f(N + 4);
    int* cursor    = (int*)alloc_f(N);
    int* partials  = (int*)alloc_f(64);
    int* ssorted   = (int*)alloc_f(E);

    // ---- CSR by dst ----
    hipMemsetAsync(cursor, 0, N * sizeof(int), stream);
    hist_kernel<<<(E + 255) / 256, 256, 0, stream>>>(edst, cursor, E);
    scan_local<<<NB, 1024, 0, stream>>>(cursor, row_start, partials, N);
    scan_offs<<<1, 64, 0, stream>>>(partials, NB);
    scan_add<<<NB, 1024, 0, stream>>>(row_start, partials, N);
    hipMemsetAsync(cursor, 0, N * sizeof(int), stream);
    scatter_kernel<<<(E + 255) / 256, 256, 0, stream>>>(esrc, edst, row_start, cursor, ssorted, E);

    // ---- pre-split inputs ----
    split_x<<<NPAD * 32 / 256, 256, 0, stream>>>(x, Xh, Xl, N);
    split_w_hi<<<(128*128 + 255)/256, 256, 0, stream>>>(W0,  B0h, 128, 128);
    split_w_hi<<<(128*128 + 255)/256, 256, 0, stream>>>(W1,  B1h, 128, 128);
    split_w_hi<<<(256*128 + 255)/256, 256, 0, stream>>>(W2,  B2h, 194, 256);
    split_w_hi<<<(256*128 + 255)/256, 256, 0, stream>>>(rW2, Brh, 194, 256);
    zero_pad2<<<24, 256, 0, stream>>>(H1h, H1l);

    const int gx = NPAD / 64;                    // 782
    const int agg_grid = N / 4;                  // 12500
    const int elr_grid = (N + 3) / 4;

    // ---- layer 0 (GEMM + fused el/er) ----
    gemm_l01<<<gx, 256, 0, stream>>>(Xh, Xl, B0h, (u16*)ftb, al0, ar0, el, er, N);
    gat_agg128<0><<<agg_grid, 256, 0, stream>>>(ftb, el, er, row_start, ssorted, nullptr, nullptr, b0, H1h, H1l);

    // ---- layer 1 (identity residual from H1h+H1l) ----
    gemm_l01<<<gx, 256, 0, stream>>>(H1h, H1l, B1h, (u16*)ftb, al1, ar1, el, er, N);
    gat_agg128<1><<<agg_grid, 256, 0, stream>>>(ftb, el, er, row_start, ssorted, H1h, H1l, b1, Xh, Xl);

    // ---- output layer: dual GEMM (W2 -> ftb bf16, rW2 -> rs2 f32), XCD-coscheduled ----
    gemm_l2<<<((gx + 7) / 8) * 32, 256, 0, stream>>>(Xh, Xl, B2h, Brh, (u16*)ftb, rs2, N);
    compute_elr<194,97><<<elr_grid, 256, 0, stream>>>(ftb, al2, ar2, el, er, N);
    gat_agg_out<<<agg_grid, 256, 0, stream>>>(ftb, el, er, row_start, ssorted, rs2, b2, out);
}

// Round 7
// 310.378 us; speedup vs baseline: 1.4910x; 1.0642x over previous
//
#include <hip/hip_runtime.h>
#include <math.h>

#define NNODES 50000
#define NEDGES 800000
#define NPAD   50048   // 782 * 64

typedef unsigned int uint;
typedef unsigned short u16;
typedef __bf16 bf16x8 __attribute__((ext_vector_type(8)));
typedef float f32x4 __attribute__((ext_vector_type(4)));

__device__ __forceinline__ float lrelu(float x){ return x > 0.f ? x : 0.2f*x; }
__device__ __forceinline__ float elu_f(float x){ return x > 0.f ? x : expm1f(x); }
__device__ __forceinline__ u16 f2bf(float f){
    uint u = __float_as_uint(f);
    return (u16)((u + 0x7fffu + ((u >> 16) & 1u)) >> 16);
}
__device__ __forceinline__ float bf2f(u16 h){ return __uint_as_float(((uint)h) << 16); }
__device__ __forceinline__ float blo(uint u){ return __uint_as_float(u << 16); }
__device__ __forceinline__ float bhi(uint u){ return __uint_as_float(u & 0xffff0000u); }

// ================= input conversion: x f32 -> Xb bf16 [NPAD][128]; also zero H1b pads =================
__global__ void split_x_bf(const float* __restrict__ x, u16* __restrict__ Xb,
                           u16* __restrict__ H1b, int N)
{
    int idx = blockIdx.x * blockDim.x + threadIdx.x;       // one float4 -> ushort4
    if (idx >= NPAD * 32) return;
    int n = idx >> 5;
    ushort4 hv = make_ushort4(0,0,0,0);
    if (n < N) {
        float4 v = ((const float4*)x)[idx];
        hv.x = f2bf(v.x); hv.y = f2bf(v.y); hv.z = f2bf(v.z); hv.w = f2bf(v.w);
    } else {
        ((ushort4*)H1b)[idx] = make_ushort4(0,0,0,0);      // zero H1 pad rows too
    }
    ((ushort4*)Xb)[idx] = hv;
}

// ================= all W's -> bf16 transposed [gcol][128] in one buffer =================
// gcol: [0,128)=W0, [128,256)=W1, [256,512)=W2(194 cols), [512,768)=rW2(194 cols)
__global__ void split_w_all(const float* __restrict__ W0, const float* __restrict__ W1,
                            const float* __restrict__ W2, const float* __restrict__ Wr,
                            u16* __restrict__ Ball)
{
    int idx = blockIdx.x * blockDim.x + threadIdx.x;       // idx = gcol*128 + k
    if (idx >= 768 * 128) return;
    int gcol = idx >> 7, k = idx & 127;
    float v;
    if (gcol < 128)      v = W0[k * 128 + gcol];
    else if (gcol < 256) v = W1[k * 128 + (gcol - 128)];
    else if (gcol < 512) { int c = gcol - 256; v = (c < 194) ? W2[k * 194 + c] : 0.f; }
    else                 { int c = gcol - 512; v = (c < 194) ? Wr[k * 194 + c] : 0.f; }
    Ball[idx] = f2bf(v);
}

// ================= GEMM layers 0/1: Cc=128, fused el/er epilogue, bf16 A =================
__global__ __launch_bounds__(256, 4)
void gemm_l01(const u16* __restrict__ Ab, const u16* __restrict__ Bh, u16* __restrict__ obf,
              const float* __restrict__ alv, const float* __restrict__ arv,
              float* __restrict__ el, float* __restrict__ er, int N)
{
    __shared__ u16 sB[128 * 136];
    const int bm = blockIdx.x * 64;
    const int tid = threadIdx.x, wid = tid >> 6, lane = tid & 63;
    const int lr = lane & 15, q = lane >> 4, lk8 = q << 3;

    bf16x8 aH[4];
    {
        size_t abase = (size_t)(bm + wid*16 + lr) * 128 + lk8;
        #pragma unroll
        for (int kt = 0; kt < 4; kt++)
            aH[kt] = *(const bf16x8*)(Ab + abase + kt*32);
    }
    // stage B: 128 cols x 128 k; 64 u16 per thread = 8 x uint4 (8 u16 each)
    {
        const int c = tid >> 1, seg = (tid & 1) * 64;
        const u16* g = Bh + (size_t)c * 128 + seg;
        u16* s = sB + c * 136 + seg;
        #pragma unroll
        for (int j = 0; j < 8; j++)
            *(uint4*)(s + j*8) = *(const uint4*)(g + j*8);
    }
    __syncthreads();

    f32x4 acc[8];
    #pragma unroll
    for (int i = 0; i < 8; i++) acc[i] = (f32x4){0.f,0.f,0.f,0.f};

    #pragma unroll
    for (int kt = 0; kt < 4; kt++)
        #pragma unroll
        for (int fs = 0; fs < 8; fs++) {
            bf16x8 b = *(const bf16x8*)(sB + (fs*16 + lr)*136 + kt*32 + lk8);
            acc[fs] = __builtin_amdgcn_mfma_f32_16x16x32_bf16(aH[kt], b, acc[fs], 0, 0, 0);
        }

    // epilogue: bf16 store + fused el/er (head0 = fs<4, head1 = fs>=4)
    float el0[4] = {0,0,0,0}, el1[4] = {0,0,0,0}, er0[4] = {0,0,0,0}, er1[4] = {0,0,0,0};
    #pragma unroll
    for (int fs = 0; fs < 8; fs++) {
        const int col = fs*16 + lr;
        const float av = alv[col], gv = arv[col];
        #pragma unroll
        for (int v = 0; v < 4; v++) {
            float f = acc[fs][v];
            int row = bm + wid*16 + q*4 + v;
            if (row < N) obf[(size_t)row * 128 + col] = f2bf(f);
            if (fs < 4) { el0[v] += f * av; er0[v] += f * gv; }
            else        { el1[v] += f * av; er1[v] += f * gv; }
        }
    }
    #pragma unroll
    for (int off = 1; off < 16; off <<= 1) {
        #pragma unroll
        for (int v = 0; v < 4; v++) {
            el0[v] += __shfl_xor(el0[v], off);
            el1[v] += __shfl_xor(el1[v], off);
            er0[v] += __shfl_xor(er0[v], off);
            er1[v] += __shfl_xor(er1[v], off);
        }
    }
    if (lr == 0) {
        #pragma unroll
        for (int v = 0; v < 4; v++) {
            int row = bm + wid*16 + q*4 + v;
            if (row < N) {
                *(float2*)(el + 2*(size_t)row) = make_float2(el0[v], el1[v]);
                *(float2*)(er + 2*(size_t)row) = make_float2(er0[v], er1[v]);
            }
        }
    }
}

// ================= GEMM layer 2: dual-matrix, 2 col-tiles, XCD-coscheduled, bf16 A/out =================
__global__ __launch_bounds__(256, 4)
void gemm_l2(const u16* __restrict__ Ab, const u16* __restrict__ B2, const u16* __restrict__ Br,
             u16* __restrict__ obf, u16* __restrict__ rs2b, int N)
{
    __shared__ u16 sB[128 * 136];
    const int bid = blockIdx.x;
    const int x = (bid >> 5) * 8 + (bid & 7);
    const int sel = (bid >> 3) & 3;
    if (x >= NPAD / 64) return;                 // block-uniform
    const bool second = (sel >= 2);             // rW2 -> rs2b
    const int coloff = (sel & 1) * 128;
    const u16* __restrict__ B = second ? Br : B2;
    u16* __restrict__ dst = second ? rs2b : obf;

    const int bm = x * 64;
    const int tid = threadIdx.x, wid = tid >> 6, lane = tid & 63;
    const int lr = lane & 15, q = lane >> 4, lk8 = q << 3;

    bf16x8 aH[4];
    {
        size_t abase = (size_t)(bm + wid*16 + lr) * 128 + lk8;
        #pragma unroll
        for (int kt = 0; kt < 4; kt++)
            aH[kt] = *(const bf16x8*)(Ab + abase + kt*32);
    }
    {
        const int c = tid >> 1, seg = (tid & 1) * 64;
        const u16* g = B + (size_t)(coloff + c) * 128 + seg;
        u16* s = sB + c * 136 + seg;
        #pragma unroll
        for (int j = 0; j < 8; j++)
            *(uint4*)(s + j*8) = *(const uint4*)(g + j*8);
    }
    __syncthreads();

    f32x4 acc[8];
    #pragma unroll
    for (int i = 0; i < 8; i++) acc[i] = (f32x4){0.f,0.f,0.f,0.f};

    #pragma unroll
    for (int kt = 0; kt < 4; kt++)
        #pragma unroll
        for (int fs = 0; fs < 8; fs++) {
            bf16x8 b = *(const bf16x8*)(sB + (fs*16 + lr)*136 + kt*32 + lk8);
            acc[fs] = __builtin_amdgcn_mfma_f32_16x16x32_bf16(aH[kt], b, acc[fs], 0, 0, 0);
        }

    #pragma unroll
    for (int fs = 0; fs < 8; fs++) {
        const int col = coloff + fs*16 + lr;
        if (col >= 194) continue;
        #pragma unroll
        for (int v = 0; v < 4; v++) {
            int row = bm + wid*16 + q*4 + v;
            if (row < N) dst[(size_t)row * 194 + col] = f2bf(acc[fs][v]);
        }
    }
}

// ================= el/er for layer 2 (C=194, D=97) =================
template<int C, int D>
__global__ void compute_elr(const uint* __restrict__ ftb, const float* __restrict__ al,
                            const float* __restrict__ ar, float* __restrict__ el,
                            float* __restrict__ er, int N)
{
    int wv = threadIdx.x >> 6, lane = threadIdx.x & 63;
    int n = blockIdx.x * 4 + wv;
    if (n >= N) return;
    const uint* row = ftb + (size_t)n * (C/2);
    float l0=0.f, l1=0.f, r0=0.f, r1=0.f;
    for (int p = lane; p < C/2; p += 64) {
        uint u = row[p];
        float f0 = blo(u), f1 = bhi(u);
        int c0 = 2*p, c1 = 2*p + 1;
        float a0 = al[c0], a1 = al[c1], g0 = ar[c0], g1 = ar[c1];
        if (c0 < D) { l0 += f0*a0; r0 += f0*g0; } else { l1 += f0*a0; r1 += f0*g0; }
        if (c1 < D) { l0 += f1*a1; r0 += f1*g1; } else { l1 += f1*a1; r1 += f1*g1; }
    }
    #pragma unroll
    for (int off = 32; off; off >>= 1) {
        l0 += __shfl_down(l0, off); l1 += __shfl_down(l1, off);
        r0 += __shfl_down(r0, off); r1 += __shfl_down(r1, off);
    }
    if (lane == 0) { el[2*n] = l0; el[2*n+1] = l1; er[2*n] = r0; er[2*n+1] = r1; }
}

// ================= CSR build (parallel decoupled scan) =================
__global__ void hist_kernel(const int* __restrict__ dst, int* __restrict__ counts, int E)
{
    int i = blockIdx.x * blockDim.x + threadIdx.x;
    if (i < E) atomicAdd(&counts[dst[i]], 1);
}

__global__ __launch_bounds__(1024)
void scan_local(const int* __restrict__ counts, int* __restrict__ row_start,
                int* __restrict__ partials, int n)
{
    __shared__ int wsum[16];
    const int tid = threadIdx.x, lane = tid & 63, wv = tid >> 6;
    const int i0 = blockIdx.x * 4096 + tid * 4;
    int v[4];
    #pragma unroll
    for (int j = 0; j < 4; j++) { int i = i0 + j; v[j] = (i < n) ? counts[i] : 0; }
    v[1] += v[0]; v[2] += v[1]; v[3] += v[2];
    int t = v[3];
    #pragma unroll
    for (int off = 1; off < 64; off <<= 1) {
        int u = __shfl_up(t, off);
        if (lane >= off) t += u;
    }
    int texcl = t - v[3];
    if (lane == 63) wsum[wv] = t;
    __syncthreads();
    int woff = 0;
    for (int w = 0; w < 16; w++) if (w < wv) woff += wsum[w];
    #pragma unroll
    for (int j = 0; j < 4; j++) { int i = i0 + j; if (i < n) row_start[i+1] = woff + texcl + v[j]; }
    if (tid == 0) {
        int tot = 0;
        for (int w = 0; w < 16; w++) tot += wsum[w];
        partials[blockIdx.x] = tot;
    }
}

__global__ void scan_offs(int* __restrict__ partials, int nb)
{
    int lane = threadIdx.x;
    int v = (lane < nb) ? partials[lane] : 0;
    int t = v;
    #pragma unroll
    for (int off = 1; off < 64; off <<= 1) {
        int u = __shfl_up(t, off);
        if (lane >= off) t += u;
    }
    if (lane < nb) partials[lane] = t - v;   // exclusive
}

__global__ __launch_bounds__(1024)
void scan_add(int* __restrict__ row_start, const int* __restrict__ partials, int n)
{
    const int tid = threadIdx.x;
    const int add = partials[blockIdx.x];
    const int i0 = blockIdx.x * 4096 + tid * 4;
    #pragma unroll
    for (int j = 0; j < 4; j++) { int i = i0 + j; if (i < n) row_start[i+1] += add; }
    if (blockIdx.x == 0 && tid == 0) row_start[0] = 0;
}

__global__ void scatter_kernel(const int* __restrict__ src, const int* __restrict__ dst,
                               const int* __restrict__ row_start, int* __restrict__ cursor,
                               int* __restrict__ src_sorted, int E)
{
    int i = blockIdx.x * blockDim.x + threadIdx.x;
    if (i < E) {
        int d = dst[i];
        int p = atomicAdd(&cursor[d], 1);
        src_sorted[row_start[d] + p] = src[i];
    }
}

// ================= aggregation, C=128 layers: one wave per dst node =================
// MODE 0: no res. MODE 1: residual from Rb (bf16). Writes bf16 out only.
template<int MODE>
__global__ __launch_bounds__(256)
void gat_agg128(const uint* __restrict__ ftb, const float* __restrict__ el,
                const float* __restrict__ er, const int* __restrict__ row_start,
                const int* __restrict__ ssorted, const u16* __restrict__ Rb,
                const float* __restrict__ bias, u16* __restrict__ Hb)
{
    __shared__ int   s_src[4][64];
    __shared__ float s_w[4][2][64];
    const int wv = threadIdx.x >> 6, lane = threadIdx.x & 63;
    const int n = blockIdx.x * 4 + wv;
    const int beg = row_start[n];
    const int deg = row_start[n+1] - beg;
    const float2 ern = *(const float2*)(er + 2*(size_t)n);
    const int h = lane >> 5;
    float ax = 0.f, ay = 0.f, dp0 = 0.f, dp1 = 0.f;

    for (int cb = 0; cb < deg; cb += 64) {
        const int cnt = min(64, deg - cb);
        float w0 = 0.f, w1 = 0.f; int s = 0;
        if (lane < cnt) {
            s = ssorted[beg + cb + lane];
            float2 e = *(const float2*)(el + 2*(size_t)s);
            w0 = __expf(lrelu(e.x + ern.x));     // no max subtraction: |logit| small
            w1 = __expf(lrelu(e.y + ern.y));
        }
        dp0 += w0; dp1 += w1;
        s_src[wv][lane] = s; s_w[wv][0][lane] = w0; s_w[wv][1][lane] = w1;
        asm volatile("s_waitcnt lgkmcnt(0)" ::: "memory");   // wave-synchronous LDS publish
        int t = 0;
        for (; t + 8 <= cnt; t += 8) {
            int4   sa = *(const int4*)&s_src[wv][t];
            int4   sb = *(const int4*)&s_src[wv][t+4];
            float4 wa = *(const float4*)&s_w[wv][h][t];
            float4 wb = *(const float4*)&s_w[wv][h][t+4];
            int   sv[8] = {sa.x,sa.y,sa.z,sa.w,sb.x,sb.y,sb.z,sb.w};
            float wj[8] = {wa.x,wa.y,wa.z,wa.w,wb.x,wb.y,wb.z,wb.w};
            uint U[8];
            #pragma unroll
            for (int j = 0; j < 8; j++) U[j] = ftb[((uint)sv[j] << 6) + lane];
            #pragma unroll
            for (int j = 0; j < 8; j++) { ax += wj[j]*blo(U[j]); ay += wj[j]*bhi(U[j]); }
        }
        for (; t + 4 <= cnt; t += 4) {
            int4   s4 = *(const int4*)&s_src[wv][t];
            float4 w4 = *(const float4*)&s_w[wv][h][t];
            int   sv[4] = {s4.x,s4.y,s4.z,s4.w};
            float wj[4] = {w4.x,w4.y,w4.z,w4.w};
            uint U[4];
            #pragma unroll
            for (int j = 0; j < 4; j++) U[j] = ftb[((uint)sv[j] << 6) + lane];
            #pragma unroll
            for (int j = 0; j < 4; j++) { ax += wj[j]*blo(U[j]); ay += wj[j]*bhi(U[j]); }
        }
        for (; t < cnt; t++) {
            int sv = s_src[wv][t];
            float w = s_w[wv][h][t];
            uint u = ftb[((uint)sv << 6) + lane];
            ax += w*blo(u); ay += w*bhi(u);
        }
    }
    #pragma unroll
    for (int off = 32; off; off >>= 1) { dp0 += __shfl_xor(dp0, off); dp1 += __shfl_xor(dp1, off); }
    const float den = (h == 0) ? dp0 : dp1;
    float r0 = (deg > 0) ? ax / den : 0.f;
    float r1 = (deg > 0) ? ay / den : 0.f;
    const int c0 = 2 * lane;
    const size_t ob = (size_t)n*128 + c0;
    const float2 bv = *(const float2*)(bias + c0);
    float v0 = r0 + bv.x, v1 = r1 + bv.y;
    if (MODE == 1) {
        ushort2 rv = *(const ushort2*)&Rb[ob];
        v0 += bf2f(rv.x);
        v1 += bf2f(rv.y);
    }
    v0 = elu_f(v0); v1 = elu_f(v1);
    *(ushort2*)&Hb[ob] = make_ushort2(f2bf(v0), f2bf(v1));
}

// ================= output-layer aggregation: one wave per dst node, C=194 D=97 =================
__global__ __launch_bounds__(256)
void gat_agg_out(const uint* __restrict__ ftb, const float* __restrict__ el,
                 const float* __restrict__ er, const int* __restrict__ row_start,
                 const int* __restrict__ ssorted, const u16* __restrict__ resb,
                 const float* __restrict__ bias, float* __restrict__ out)
{
    __shared__ int   s_src[4][64];
    __shared__ float s_w[4][2][64];
    __shared__ float s_a1[4][97];
    const int wv = threadIdx.x >> 6, lane = threadIdx.x & 63;
    const int n = blockIdx.x * 4 + wv;
    if (n >= NNODES - 1) return;                 // wave-uniform exit, no barriers used
    const int beg = row_start[n];
    const int deg = row_start[n+1] - beg;
    const float2 ern = *(const float2*)(er + 2*(size_t)n);
    const bool dual = (lane < 33);
    const bool xh0 = (lane <= 48), yh0 = (lane <= 47);
    float ax1=0.f, ay1=0.f, ax2=0.f, ay2=0.f, dp0=0.f, dp1=0.f;

    for (int cb = 0; cb < deg; cb += 64) {
        const int cnt = min(64, deg - cb);
        float w0 = 0.f, w1 = 0.f; int s = 0;
        if (lane < cnt) {
            s = ssorted[beg + cb + lane];
            float2 e = *(const float2*)(el + 2*(size_t)s);
            w0 = __expf(lrelu(e.x + ern.x));
            w1 = __expf(lrelu(e.y + ern.y));
        }
        dp0 += w0; dp1 += w1;
        s_src[wv][lane] = s; s_w[wv][0][lane] = w0; s_w[wv][1][lane] = w1;
        asm volatile("s_waitcnt lgkmcnt(0)" ::: "memory");
        int t = 0;
        for (; t + 8 <= cnt; t += 8) {
            int4   sa = *(const int4*)&s_src[wv][t];
            int4   sb = *(const int4*)&s_src[wv][t+4];
            float4 p0a = *(const float4*)&s_w[wv][0][t];
            float4 p0b = *(const float4*)&s_w[wv][0][t+4];
            float4 p1a = *(const float4*)&s_w[wv][1][t];
            float4 p1b = *(const float4*)&s_w[wv][1][t+4];
            int   sv[8] = {sa.x,sa.y,sa.z,sa.w,sb.x,sb.y,sb.z,sb.w};
            float f0[8] = {p0a.x,p0a.y,p0a.z,p0a.w,p0b.x,p0b.y,p0b.z,p0b.w};
            float f1[8] = {p1a.x,p1a.y,p1a.z,p1a.w,p1b.x,p1b.y,p1b.z,p1b.w};
            uint U1[8], U2[8];
            #pragma unroll
            for (int j = 0; j < 8; j++) {
                const uint* row = ftb + (uint)sv[j] * 97u;
                U1[j] = row[lane];
                U2[j] = dual ? row[64 + lane] : 0u;
            }
            #pragma unroll
            for (int j = 0; j < 8; j++) {
                float wx = xh0 ? f0[j] : f1[j], wy = yh0 ? f0[j] : f1[j];
                ax1 += wx*blo(U1[j]); ay1 += wy*bhi(U1[j]);
                ax2 += f1[j]*blo(U2[j]); ay2 += f1[j]*bhi(U2[j]);
            }
        }
        for (; t < cnt; t++) {
            int sv = s_src[wv][t];
            float f0 = s_w[wv][0][t], f1 = s_w[wv][1][t];
            const uint* row = ftb + (uint)sv * 97u;
            uint u1 = row[lane];
            uint u2 = dual ? row[64 + lane] : 0u;
            float wx = xh0 ? f0 : f1, wy = yh0 ? f0 : f1;
            ax1 += wx*blo(u1); ay1 += wy*bhi(u1);
            ax2 += f1*blo(u2); ay2 += f1*bhi(u2);
        }
    }
    #pragma unroll
    for (int off = 32; off; off >>= 1) { dp0 += __shfl_xor(dp0, off); dp1 += __shfl_xor(dp1, off); }
    const float i0 = (deg > 0) ? 1.f/dp0 : 0.f;
    const float i1 = (deg > 0) ? 1.f/dp1 : 0.f;
    float A0x = ax1 * (xh0 ? i0 : i1);
    float A0y = ay1 * (yh0 ? i0 : i1);
    float A2x = ax2 * i1, A2y = ay2 * i1;
    if (lane == 48)      s_a1[wv][0] = A0y;
    else if (lane >= 49) { s_a1[wv][2*lane - 97] = A0x; s_a1[wv][2*lane - 96] = A0y; }
    if (dual)            { s_a1[wv][31 + 2*lane] = A2x; s_a1[wv][32 + 2*lane] = A2y; }
    asm volatile("s_waitcnt lgkmcnt(0)" ::: "memory");
    if (lane <= 48) {
        const int c = 2 * lane;
        const u16* rr = resb + (size_t)n * 194;
        out[(size_t)n*97 + c] = 0.5f*(A0x + s_a1[wv][c] + bf2f(rr[c]) + bf2f(rr[97+c]) + bias[c] + bias[97+c]);
        if (lane < 48)
            out[(size_t)n*97 + c + 1] = 0.5f*(A0y + s_a1[wv][c+1] + bf2f(rr[c+1]) + bf2f(rr[98+c]) + bias[c+1] + bias[98+c]);
    }
}

extern "C" void kernel_launch(void* const* d_in, const int* in_sizes, int n_in,
                              void* d_out, int out_size, void* d_ws, size_t ws_size,
                              hipStream_t stream)
{
    const float* x   = (const float*)d_in[0];
    const int*   esrc= (const int*)  d_in[1];
    const int*   edst= (const int*)  d_in[2];
    const float* W0  = (const float*)d_in[3];
    const float* al0 = (const float*)d_in[4];
    const float* ar0 = (const float*)d_in[5];
    const float* b0  = (const float*)d_in[6];
    const float* W1  = (const float*)d_in[7];
    const float* al1 = (const float*)d_in[8];
    const float* ar1 = (const float*)d_in[9];
    const float* b1  = (const float*)d_in[10];
    const float* W2  = (const float*)d_in[11];
    const float* al2 = (const float*)d_in[12];
    const float* ar2 = (const float*)d_in[13];
    const float* b2  = (const float*)d_in[14];
    const float* rW2 = (const float*)d_in[15];
    float* out = (float*)d_out;

    const int N = NNODES, E = NEDGES;
    const int NB = (N + 4095) / 4096;            // 13 scan tiles
    float* ws = (float*)d_ws;
    size_t o = 0;
    auto alloc_f = [&](size_t count) { float* p = ws + o; o += (count + 3) & ~(size_t)3; return p; };
    float* el   = alloc_f((size_t)N * 2);
    float* er   = alloc_f((size_t)N * 2);
    uint*  ftb  = (uint*)alloc_f((size_t)N * 97);          // bf16 ft (u32-pair view)
    u16*   rs2b = (u16*)alloc_f((size_t)N * 97);           // bf16 residual [N][194]
    u16*   Xb   = (u16*)alloc_f((size_t)NPAD * 64);        // bf16 [NPAD][128]
    u16*   H1b  = (u16*)alloc_f((size_t)NPAD * 64);
    u16*   Ball = (u16*)alloc_f(768 * 64);                 // all W's bf16 transposed
    int* row_start = (int*)alloc_f(N + 4);
    int* cursor    = (int*)alloc_f(N);
    int* partials  = (int*)alloc_f(64);
    int* ssorted   = (int*)alloc_f(E);
    u16* B0h = Ball, *B1h = Ball + 128*128, *B2h = Ball + 256*128, *Brh = Ball + 512*128;

    // ---- CSR by dst ----
    hipMemsetAsync(cursor, 0, N * sizeof(int), stream);
    hist_kernel<<<(E + 255) / 256, 256, 0, stream>>>(edst, cursor, E);
    scan_local<<<NB, 1024, 0, stream>>>(cursor, row_start, partials, N);
    scan_offs<<<1, 64, 0, stream>>>(partials, NB);
    scan_add<<<NB, 1024, 0, stream>>>(row_start, partials, N);
    hipMemsetAsync(cursor, 0, N * sizeof(int), stream);
    scatter_kernel<<<(E + 255) / 256, 256, 0, stream>>>(esrc, edst, row_start, cursor, ssorted, E);

    // ---- input conversion ----
    split_x_bf<<<NPAD * 32 / 256, 256, 0, stream>>>(x, Xb, H1b, N);
    split_w_all<<<768 * 128 / 256, 256, 0, stream>>>(W0, W1, W2, rW2, Ball);

    const int gx = NPAD / 64;                    // 782
    const int agg_grid = N / 4;                  // 12500
    const int elr_grid = (N + 3) / 4;

    // ---- layer 0 (GEMM + fused el/er) ----
    gemm_l01<<<gx, 256, 0, stream>>>(Xb, B0h, (u16*)ftb, al0, ar0, el, er, N);
    gat_agg128<0><<<agg_grid, 256, 0, stream>>>(ftb, el, er, row_start, ssorted, nullptr, b0, H1b);

    // ---- layer 1 (identity residual from H1b) ----
    gemm_l01<<<gx, 256, 0, stream>>>(H1b, B1h, (u16*)ftb, al1, ar1, el, er, N);
    gat_agg128<1><<<agg_grid, 256, 0, stream>>>(ftb, el, er, row_start, ssorted, H1b, b1, Xb);

    // ---- output layer: dual GEMM (W2 -> ftb, rW2 -> rs2b), XCD-coscheduled ----
    gemm_l2<<<((gx + 7) / 8) * 32, 256, 0, stream>>>(Xb, B2h, Brh, (u16*)ftb, rs2b, N);
    compute_elr<194,97><<<elr_grid, 256, 0, stream>>>(ftb, al2, ar2, el, er, N);
    gat_agg_out<<<agg_grid, 256, 0, stream>>>(ftb, el, er, row_start, ssorted, rs2b, b2, out);
}

// Round 8
// 296.983 us; speedup vs baseline: 1.5582x; 1.0451x over previous
//
#include <hip/hip_runtime.h>
#include <math.h>

#define NNODES 50000
#define NEDGES 800000
#define NPAD   50048   // 782 * 64

typedef unsigned int uint;
typedef unsigned short u16;
typedef __bf16 bf16x8 __attribute__((ext_vector_type(8)));
typedef float f32x4 __attribute__((ext_vector_type(4)));

__device__ __forceinline__ float lrelu(float x){ return x > 0.f ? x : 0.2f*x; }
__device__ __forceinline__ float elu_f(float x){ return x > 0.f ? x : expm1f(x); }
__device__ __forceinline__ u16 f2bf(float f){
    uint u = __float_as_uint(f);
    return (u16)((u + 0x7fffu + ((u >> 16) & 1u)) >> 16);
}
__device__ __forceinline__ float bf2f(u16 h){ return __uint_as_float(((uint)h) << 16); }
__device__ __forceinline__ float blo(uint u){ return __uint_as_float(u << 16); }
__device__ __forceinline__ float bhi(uint u){ return __uint_as_float(u & 0xffff0000u); }

// ================= one-shot prep: x cast, W0/W1 transpose, Bf build, alp2/arp2, cb =================
// idx ranges: [0,R0) x->Xb (+H1b pad zero); [R0,R1) B01; [R1,R2) Bf; [R2,R3) alp2/arp2; [R3,R4) cb
#define R0 (NPAD*32)
#define R1 (R0 + 256*128)
#define R2 (R1 + 128*384)
#define R3 (R2 + 256)
#define R4 (R3 + 128)
__global__ void prep_all(const float* __restrict__ x,
                         const float* __restrict__ W0, const float* __restrict__ W1,
                         const float* __restrict__ W2, const float* __restrict__ Wr,
                         const float* __restrict__ al2, const float* __restrict__ ar2,
                         const float* __restrict__ b2,
                         u16* __restrict__ Xb, u16* __restrict__ H1b,
                         u16* __restrict__ B01, u16* __restrict__ Bf,
                         float* __restrict__ alp2, float* __restrict__ arp2,
                         float* __restrict__ cb, int N)
{
    int idx = blockIdx.x * blockDim.x + threadIdx.x;
    if (idx < R0) {                                        // x: one float4 -> ushort4
        int n = idx >> 5;
        ushort4 hv = make_ushort4(0,0,0,0);
        if (n < N) {
            float4 v = ((const float4*)x)[idx];
            hv.x = f2bf(v.x); hv.y = f2bf(v.y); hv.z = f2bf(v.z); hv.w = f2bf(v.w);
        } else {
            ((ushort4*)H1b)[idx] = make_ushort4(0,0,0,0);  // zero H1 pad rows
        }
        ((ushort4*)Xb)[idx] = hv;
    } else if (idx < R1) {                                 // W0/W1 transposed bf16 [gcol][128]
        int j = idx - R0, gcol = j >> 7, k = j & 127;
        float v = (gcol < 128) ? W0[k*128 + gcol] : W1[k*128 + (gcol - 128)];
        B01[j] = f2bf(v);
    } else if (idx < R2) {                                 // Bf [128 cols][384 k]
        int j = idx - R1, c = j / 384, k = j - c*384;
        float v = 0.f;
        if (c < 97) {
            if (k < 128)      v = W2[k*194 + c];
            else if (k < 256) v = W2[(k-128)*194 + 97 + c];
            else              v = Wr[(k-256)*194 + c] + Wr[(k-256)*194 + 97 + c];
        }
        Bf[c*384 + k] = f2bf(v);
    } else if (idx < R3) {                                 // alp2/arp2 [2][128]
        int t = idx - R2, k = t & 127, h = t >> 7;
        float sl = 0.f, sr = 0.f;
        for (int d = 0; d < 97; d++) {
            float w = W2[k*194 + h*97 + d];
            sl += w * al2[h*97 + d];
            sr += w * ar2[h*97 + d];
        }
        alp2[h*128 + k] = sl;
        arp2[h*128 + k] = sr;
    } else if (idx < R4) {                                 // cb
        int c = idx - R3;
        if (c < 97) cb[c] = 0.5f * (b2[c] + b2[97 + c]);
    }
}

// ================= GEMM layers 0/1: Cc=128, fused el/er epilogue, bf16 A =================
__global__ __launch_bounds__(256, 4)
void gemm_l01(const u16* __restrict__ Ab, const u16* __restrict__ Bh, u16* __restrict__ obf,
              const float* __restrict__ alv, const float* __restrict__ arv,
              float* __restrict__ el, float* __restrict__ er, int N)
{
    __shared__ u16 sB[128 * 136];
    const int bm = blockIdx.x * 64;
    const int tid = threadIdx.x, wid = tid >> 6, lane = tid & 63;
    const int lr = lane & 15, q = lane >> 4, lk8 = q << 3;

    bf16x8 aH[4];
    {
        size_t abase = (size_t)(bm + wid*16 + lr) * 128 + lk8;
        #pragma unroll
        for (int kt = 0; kt < 4; kt++)
            aH[kt] = *(const bf16x8*)(Ab + abase + kt*32);
    }
    {
        const int c = tid >> 1, seg = (tid & 1) * 64;
        const u16* g = Bh + (size_t)c * 128 + seg;
        u16* s = sB + c * 136 + seg;
        #pragma unroll
        for (int j = 0; j < 8; j++)
            *(uint4*)(s + j*8) = *(const uint4*)(g + j*8);
    }
    __syncthreads();

    f32x4 acc[8];
    #pragma unroll
    for (int i = 0; i < 8; i++) acc[i] = (f32x4){0.f,0.f,0.f,0.f};

    #pragma unroll
    for (int kt = 0; kt < 4; kt++)
        #pragma unroll
        for (int fs = 0; fs < 8; fs++) {
            bf16x8 b = *(const bf16x8*)(sB + (fs*16 + lr)*136 + kt*32 + lk8);
            acc[fs] = __builtin_amdgcn_mfma_f32_16x16x32_bf16(aH[kt], b, acc[fs], 0, 0, 0);
        }

    float el0[4] = {0,0,0,0}, el1[4] = {0,0,0,0}, er0[4] = {0,0,0,0}, er1[4] = {0,0,0,0};
    #pragma unroll
    for (int fs = 0; fs < 8; fs++) {
        const int col = fs*16 + lr;
        const float av = alv[col], gv = arv[col];
        #pragma unroll
        for (int v = 0; v < 4; v++) {
            float f = acc[fs][v];
            int row = bm + wid*16 + q*4 + v;
            if (row < N) obf[(size_t)row * 128 + col] = f2bf(f);
            if (fs < 4) { el0[v] += f * av; er0[v] += f * gv; }
            else        { el1[v] += f * av; er1[v] += f * gv; }
        }
    }
    #pragma unroll
    for (int off = 1; off < 16; off <<= 1) {
        #pragma unroll
        for (int v = 0; v < 4; v++) {
            el0[v] += __shfl_xor(el0[v], off);
            el1[v] += __shfl_xor(el1[v], off);
            er0[v] += __shfl_xor(er0[v], off);
            er1[v] += __shfl_xor(er1[v], off);
        }
    }
    if (lr == 0) {
        #pragma unroll
        for (int v = 0; v < 4; v++) {
            int row = bm + wid*16 + q*4 + v;
            if (row < N) {
                *(float2*)(el + 2*(size_t)row) = make_float2(el0[v], el1[v]);
                *(float2*)(er + 2*(size_t)row) = make_float2(er0[v], er1[v]);
            }
        }
    }
}

// ================= final GEMM: out = 0.5*([agg0|agg1|h2] @ Bf) + cb =================
// K=384 (k<256 from agg01, k>=256 from h2). 2 col-tiles of 64, XCD-coscheduled.
__global__ __launch_bounds__(256, 3)
void gemm_final(const u16* __restrict__ agg01, const u16* __restrict__ h2b,
                const u16* __restrict__ Bf, const float* __restrict__ cb,
                float* __restrict__ out, int N)
{
    __shared__ u16 sB[64 * 392];
    const int bid = blockIdx.x;
    const int x = (bid >> 4) * 8 + (bid & 7);
    const int ct = (bid >> 3) & 1;
    if (x >= NPAD / 64) return;                 // block-uniform
    const int bm = x * 64;
    const int tid = threadIdx.x, wid = tid >> 6, lane = tid & 63;
    const int lr = lane & 15, q = lane >> 4, lk8 = q << 3;

    bf16x8 aF[12];
    {
        const int row = bm + wid*16 + lr;
        const u16* pa = agg01 + (size_t)row * 256;
        #pragma unroll
        for (int kt = 0; kt < 8; kt++)
            aF[kt] = *(const bf16x8*)(pa + kt*32 + lk8);
        const u16* ph = h2b + (size_t)row * 128;
        #pragma unroll
        for (int kt = 0; kt < 4; kt++)
            aF[8 + kt] = *(const bf16x8*)(ph + kt*32 + lk8);
    }
    {
        const int c = tid >> 2, seg = (tid & 3) * 96;      // 96 u16 = 12 x uint4
        const u16* g = Bf + (size_t)(ct*64 + c) * 384 + seg;
        u16* s = sB + c * 392 + seg;
        #pragma unroll
        for (int j = 0; j < 12; j++)
            *(uint4*)(s + j*8) = *(const uint4*)(g + j*8);
    }
    __syncthreads();

    f32x4 acc[4];
    #pragma unroll
    for (int i = 0; i < 4; i++) acc[i] = (f32x4){0.f,0.f,0.f,0.f};

    #pragma unroll
    for (int kt = 0; kt < 12; kt++)
        #pragma unroll
        for (int fs = 0; fs < 4; fs++) {
            bf16x8 b = *(const bf16x8*)(sB + (fs*16 + lr)*392 + kt*32 + lk8);
            acc[fs] = __builtin_amdgcn_mfma_f32_16x16x32_bf16(aF[kt], b, acc[fs], 0, 0, 0);
        }

    #pragma unroll
    for (int fs = 0; fs < 4; fs++) {
        const int col = ct*64 + fs*16 + lr;
        if (col >= 97) continue;
        const float cbc = cb[col];
        #pragma unroll
        for (int v = 0; v < 4; v++) {
            int row = bm + wid*16 + q*4 + v;
            if (row < N - 1) out[(size_t)row * 97 + col] = 0.5f * acc[fs][v] + cbc;
        }
    }
}

// ================= CSR build =================
__global__ void hist_kernel(const int* __restrict__ dst, int* __restrict__ counts, int E)
{
    int i = blockIdx.x * blockDim.x + threadIdx.x;
    if (i < E) atomicAdd(&counts[dst[i]], 1);
}

// single-pass decoupled-lookback scan; also initializes cursor (= exclusive start)
__global__ __launch_bounds__(1024)
void scan_dl(int* __restrict__ cnt_cur, int* __restrict__ row_start,
             int* __restrict__ flags, int* __restrict__ prefixes, int n)
{
    __shared__ int wsum[16];
    __shared__ int sExc;
    const int tid = threadIdx.x, lane = tid & 63, wv = tid >> 6;
    const int i0 = blockIdx.x * 4096 + tid * 4;
    int c[4], v[4];
    #pragma unroll
    for (int j = 0; j < 4; j++) { int i = i0 + j; c[j] = (i < n) ? cnt_cur[i] : 0; }
    v[0] = c[0]; v[1] = v[0] + c[1]; v[2] = v[1] + c[2]; v[3] = v[2] + c[3];
    int t = v[3];
    #pragma unroll
    for (int off = 1; off < 64; off <<= 1) {
        int u = __shfl_up(t, off);
        if (lane >= off) t += u;
    }
    int texcl = t - v[3];
    if (lane == 63) wsum[wv] = t;
    __syncthreads();
    if (tid == 0) {
        int tot = 0;
        #pragma unroll
        for (int w = 0; w < 16; w++) tot += wsum[w];
        int exc = 0;
        if (blockIdx.x > 0) {
            while (atomicAdd(&flags[blockIdx.x - 1], 0) == 0) __builtin_amdgcn_s_sleep(2);
            exc = atomicAdd(&prefixes[blockIdx.x - 1], 0);
        } else {
            row_start[0] = 0;
        }
        atomicExch(&prefixes[blockIdx.x], exc + tot);
        __threadfence();
        atomicExch(&flags[blockIdx.x], 1);
        sExc = exc;
    }
    __syncthreads();
    int woff = sExc + texcl;
    for (int w = 0; w < 16; w++) if (w < wv) woff += wsum[w];
    #pragma unroll
    for (int j = 0; j < 4; j++) {
        int i = i0 + j;
        if (i < n) {
            int inc = woff + v[j];
            row_start[i + 1] = inc;
            cnt_cur[i] = inc - c[j];                       // cursor init = exclusive start
        }
    }
}

__global__ void scatter_kernel(const int* __restrict__ src, const int* __restrict__ dst,
                               int* __restrict__ cursor, int* __restrict__ src_sorted, int E)
{
    int i = blockIdx.x * blockDim.x + threadIdx.x;
    if (i < E) {
        int p = atomicAdd(&cursor[dst[i]], 1);
        src_sorted[p] = src[i];
    }
}

// ================= aggregation, C=128 layers: one wave per dst node =================
// MODE 0: no res. MODE 1: residual from Rb + fused el2/er2 (= h2 . alp2/arp2) epilogue.
template<int MODE>
__global__ __launch_bounds__(256)
void gat_agg128(const uint* __restrict__ ftb, const float* __restrict__ el,
                const float* __restrict__ er, const int* __restrict__ row_start,
                const int* __restrict__ ssorted, const u16* __restrict__ Rb,
                const float* __restrict__ bias, u16* __restrict__ Hb,
                const float* __restrict__ alp2, const float* __restrict__ arp2,
                float* __restrict__ el2, float* __restrict__ er2)
{
    __shared__ int   s_src[4][64];
    __shared__ float s_w[4][2][64];
    const int wv = threadIdx.x >> 6, lane = threadIdx.x & 63;
    const int n = blockIdx.x * 4 + wv;
    const int beg = row_start[n];
    const int deg = row_start[n+1] - beg;
    const float2 ern = *(const float2*)(er + 2*(size_t)n);
    const int h = lane >> 5;
    float ax = 0.f, ay = 0.f, dp0 = 0.f, dp1 = 0.f;

    for (int cb = 0; cb < deg; cb += 64) {
        const int cnt = min(64, deg - cb);
        float w0 = 0.f, w1 = 0.f; int s = 0;
        if (lane < cnt) {
            s = ssorted[beg + cb + lane];
            float2 e = *(const float2*)(el + 2*(size_t)s);
            w0 = __expf(lrelu(e.x + ern.x));     // no max subtraction: |logit| small
            w1 = __expf(lrelu(e.y + ern.y));
        }
        dp0 += w0; dp1 += w1;
        s_src[wv][lane] = s; s_w[wv][0][lane] = w0; s_w[wv][1][lane] = w1;
        asm volatile("s_waitcnt lgkmcnt(0)" ::: "memory");   // wave-synchronous LDS publish
        int t = 0;
        for (; t + 8 <= cnt; t += 8) {
            int4   sa = *(const int4*)&s_src[wv][t];
            int4   sb = *(const int4*)&s_src[wv][t+4];
            float4 wa = *(const float4*)&s_w[wv][h][t];
            float4 wb = *(const float4*)&s_w[wv][h][t+4];
            int   sv[8] = {sa.x,sa.y,sa.z,sa.w,sb.x,sb.y,sb.z,sb.w};
            float wj[8] = {wa.x,wa.y,wa.z,wa.w,wb.x,wb.y,wb.z,wb.w};
            uint U[8];
            #pragma unroll
            for (int j = 0; j < 8; j++) U[j] = ftb[((uint)sv[j] << 6) + lane];
            #pragma unroll
            for (int j = 0; j < 8; j++) { ax += wj[j]*blo(U[j]); ay += wj[j]*bhi(U[j]); }
        }
        for (; t < cnt; t++) {
            int sv = s_src[wv][t];
            float w = s_w[wv][h][t];
            uint u = ftb[((uint)sv << 6) + lane];
            ax += w*blo(u); ay += w*bhi(u);
        }
    }
    #pragma unroll
    for (int off = 32; off; off >>= 1) { dp0 += __shfl_xor(dp0, off); dp1 += __shfl_xor(dp1, off); }
    const float den = (h == 0) ? dp0 : dp1;
    float r0 = (deg > 0) ? ax / den : 0.f;
    float r1 = (deg > 0) ? ay / den : 0.f;
    const int c0 = 2 * lane;
    const size_t ob = (size_t)n*128 + c0;
    const float2 bv = *(const float2*)(bias + c0);
    float v0 = r0 + bv.x, v1 = r1 + bv.y;
    if (MODE == 1) {
        ushort2 rv = *(const ushort2*)&Rb[ob];
        v0 += bf2f(rv.x);
        v1 += bf2f(rv.y);
    }
    v0 = elu_f(v0); v1 = elu_f(v1);
    *(ushort2*)&Hb[ob] = make_ushort2(f2bf(v0), f2bf(v1));

    if constexpr (MODE == 1) {
        // fused el2/er2: el2[n,h] = sum_k h2[n,k] * alp2[h,k]
        float2 a0 = *(const float2*)(alp2 + c0);
        float2 a1 = *(const float2*)(alp2 + 128 + c0);
        float2 g0 = *(const float2*)(arp2 + c0);
        float2 g1 = *(const float2*)(arp2 + 128 + c0);
        float e0 = v0*a0.x + v1*a0.y;
        float e1 = v0*a1.x + v1*a1.y;
        float f0 = v0*g0.x + v1*g0.y;
        float f1 = v0*g1.x + v1*g1.y;
        #pragma unroll
        for (int off = 32; off; off >>= 1) {
            e0 += __shfl_xor(e0, off); e1 += __shfl_xor(e1, off);
            f0 += __shfl_xor(f0, off); f1 += __shfl_xor(f1, off);
        }
        if (lane == 0) {
            *(float2*)(el2 + 2*(size_t)n) = make_float2(e0, e1);
            *(float2*)(er2 + 2*(size_t)n) = make_float2(f0, f1);
        }
    }
}

// ================= layer-2 aggregation on h2 (linearity trick): per-head 128-dim aggregates =================
__global__ __launch_bounds__(256)
void gat_agg_out2(const uint* __restrict__ h2u, const float* __restrict__ el,
                  const float* __restrict__ er, const int* __restrict__ row_start,
                  const int* __restrict__ ssorted, u16* __restrict__ agg01)
{
    __shared__ int   s_src[4][64];
    __shared__ float s_w[4][2][64];
    const int wv = threadIdx.x >> 6, lane = threadIdx.x & 63;
    const int n = blockIdx.x * 4 + wv;
    const int beg = row_start[n];
    const int deg = row_start[n+1] - beg;
    const float2 ern = *(const float2*)(er + 2*(size_t)n);
    float ax0 = 0.f, ay0 = 0.f, ax1 = 0.f, ay1 = 0.f, dp0 = 0.f, dp1 = 0.f;

    for (int cb = 0; cb < deg; cb += 64) {
        const int cnt = min(64, deg - cb);
        float w0 = 0.f, w1 = 0.f; int s = 0;
        if (lane < cnt) {
            s = ssorted[beg + cb + lane];
            float2 e = *(const float2*)(el + 2*(size_t)s);
            w0 = __expf(lrelu(e.x + ern.x));
            w1 = __expf(lrelu(e.y + ern.y));
        }
        dp0 += w0; dp1 += w1;
        s_src[wv][lane] = s; s_w[wv][0][lane] = w0; s_w[wv][1][lane] = w1;
        asm volatile("s_waitcnt lgkmcnt(0)" ::: "memory");
        int t = 0;
        for (; t + 8 <= cnt; t += 8) {
            int4   sa = *(const int4*)&s_src[wv][t];
            int4   sb = *(const int4*)&s_src[wv][t+4];
            float4 p0a = *(const float4*)&s_w[wv][0][t];
            float4 p0b = *(const float4*)&s_w[wv][0][t+4];
            float4 p1a = *(const float4*)&s_w[wv][1][t];
            float4 p1b = *(const float4*)&s_w[wv][1][t+4];
            int   sv[8] = {sa.x,sa.y,sa.z,sa.w,sb.x,sb.y,sb.z,sb.w};
            float f0[8] = {p0a.x,p0a.y,p0a.z,p0a.w,p0b.x,p0b.y,p0b.z,p0b.w};
            float f1[8] = {p1a.x,p1a.y,p1a.z,p1a.w,p1b.x,p1b.y,p1b.z,p1b.w};
            uint U[8];
            #pragma unroll
            for (int j = 0; j < 8; j++) U[j] = h2u[((uint)sv[j] << 6) + lane];
            #pragma unroll
            for (int j = 0; j < 8; j++) {
                float lo = blo(U[j]), hi = bhi(U[j]);
                ax0 += f0[j]*lo; ay0 += f0[j]*hi;
                ax1 += f1[j]*lo; ay1 += f1[j]*hi;
            }
        }
        for (; t < cnt; t++) {
            int sv = s_src[wv][t];
            float f0 = s_w[wv][0][t], f1 = s_w[wv][1][t];
            uint u = h2u[((uint)sv << 6) + lane];
            float lo = blo(u), hi = bhi(u);
            ax0 += f0*lo; ay0 += f0*hi;
            ax1 += f1*lo; ay1 += f1*hi;
        }
    }
    #pragma unroll
    for (int off = 32; off; off >>= 1) { dp0 += __shfl_xor(dp0, off); dp1 += __shfl_xor(dp1, off); }
    const float i0 = (deg > 0) ? 1.f/dp0 : 0.f;
    const float i1 = (deg > 0) ? 1.f/dp1 : 0.f;
    const int c0 = 2 * lane;
    *(ushort2*)&agg01[(size_t)n*256 + c0]       = make_ushort2(f2bf(ax0*i0), f2bf(ay0*i0));
    *(ushort2*)&agg01[(size_t)n*256 + 128 + c0] = make_ushort2(f2bf(ax1*i1), f2bf(ay1*i1));
}

extern "C" void kernel_launch(void* const* d_in, const int* in_sizes, int n_in,
                              void* d_out, int out_size, void* d_ws, size_t ws_size,
                              hipStream_t stream)
{
    const float* x   = (const float*)d_in[0];
    const int*   esrc= (const int*)  d_in[1];
    const int*   edst= (const int*)  d_in[2];
    const float* W0  = (const float*)d_in[3];
    const float* al0 = (const float*)d_in[4];
    const float* ar0 = (const float*)d_in[5];
    const float* b0  = (const float*)d_in[6];
    const float* W1  = (const float*)d_in[7];
    const float* al1 = (const float*)d_in[8];
    const float* ar1 = (const float*)d_in[9];
    const float* b1  = (const float*)d_in[10];
    const float* W2  = (const float*)d_in[11];
    const float* al2 = (const float*)d_in[12];
    const float* ar2 = (const float*)d_in[13];
    const float* b2  = (const float*)d_in[14];
    const float* rW2 = (const float*)d_in[15];
    float* out = (float*)d_out;

    const int N = NNODES, E = NEDGES;
    const int NB = (N + 4095) / 4096;            // 13 scan tiles
    float* ws = (float*)d_ws;
    size_t o = 0;
    auto alloc_f = [&](size_t count) { float* p = ws + o; o += (count + 3) & ~(size_t)3; return p; };
    float* el    = alloc_f((size_t)N * 2);
    float* er    = alloc_f((size_t)N * 2);
    float* el2   = alloc_f((size_t)N * 2);
    float* er2   = alloc_f((size_t)N * 2);
    uint*  ftb   = (uint*)alloc_f((size_t)N * 64);         // bf16 ft [N][128]
    u16*   agg01 = (u16*)alloc_f((size_t)NPAD * 128);      // bf16 [NPAD][256]
    u16*   Xb    = (u16*)alloc_f((size_t)NPAD * 64);       // bf16 [NPAD][128] (x, then h2)
    u16*   H1b   = (u16*)alloc_f((size_t)NPAD * 64);
    u16*   B01   = (u16*)alloc_f(256 * 64);                // W0|W1 transposed bf16
    u16*   Bf    = (u16*)alloc_f(128 * 192);               // final-GEMM B' [128][384]
    float* alp2  = alloc_f(256);
    float* arp2  = alloc_f(256);
    float* cbv   = alloc_f(128);
    int* row_start = (int*)alloc_f(N + 4);
    int* cursor    = (int*)alloc_f(N + 64);                // counts/cursor + flags + prefixes
    int* flags     = cursor + N;
    int* prefixes  = cursor + N + 16;
    int* ssorted   = (int*)alloc_f(E);

    // ---- CSR by dst: memset, hist, single-pass scan (inits cursor), scatter ----
    hipMemsetAsync(cursor, 0, (N + 64) * sizeof(int), stream);
    hist_kernel<<<(E + 255) / 256, 256, 0, stream>>>(edst, cursor, E);
    scan_dl<<<NB, 1024, 0, stream>>>(cursor, row_start, flags, prefixes, N);
    scatter_kernel<<<(E + 255) / 256, 256, 0, stream>>>(esrc, edst, cursor, ssorted, E);

    // ---- all input prep in one kernel ----
    prep_all<<<(R4 + 255) / 256, 256, 0, stream>>>(x, W0, W1, W2, rW2, al2, ar2, b2,
                                                   Xb, H1b, B01, Bf, alp2, arp2, cbv, N);

    const int gx = NPAD / 64;                    // 782
    const int agg_grid = N / 4;                  // 12500

    // ---- layer 0 (GEMM + fused el/er) ----
    gemm_l01<<<gx, 256, 0, stream>>>(Xb, B01, (u16*)ftb, al0, ar0, el, er, N);
    gat_agg128<0><<<agg_grid, 256, 0, stream>>>(ftb, el, er, row_start, ssorted,
                                                nullptr, b0, H1b, nullptr, nullptr, nullptr, nullptr);

    // ---- layer 1 (identity residual; epilogue computes h2 + el2/er2) ----
    gemm_l01<<<gx, 256, 0, stream>>>(H1b, B01 + 128*128, (u16*)ftb, al1, ar1, el, er, N);
    gat_agg128<1><<<agg_grid, 256, 0, stream>>>(ftb, el, er, row_start, ssorted,
                                                H1b, b1, Xb, alp2, arp2, el2, er2);

    // ---- layer 2: aggregate h2 per head, then fused output GEMM ----
    gat_agg_out2<<<agg_grid, 256, 0, stream>>>((uint*)Xb, el2, er2, row_start, ssorted, agg01);
    gemm_final<<<((gx + 7) / 8) * 16, 256, 0, stream>>>(agg01, Xb, Bf, cbv, out, N);
}

// Round 9
// 281.185 us; speedup vs baseline: 1.6458x; 1.0562x over previous
//
#include <hip/hip_runtime.h>
#include <math.h>

#define NNODES 50000
#define NEDGES 800000
#define NPAD   50048   // 782 * 64
#define NSLICE 8
#define SLICEN (NNODES / NSLICE)   // 6250

typedef unsigned int uint;
typedef unsigned short u16;
typedef __bf16 bf16x8 __attribute__((ext_vector_type(8)));
typedef float f32x4 __attribute__((ext_vector_type(4)));

__device__ __forceinline__ float lrelu(float x){ return x > 0.f ? x : 0.2f*x; }
__device__ __forceinline__ float elu_f(float x){ return x > 0.f ? x : expm1f(x); }
__device__ __forceinline__ u16 f2bf(float f){
    uint u = __float_as_uint(f);
    return (u16)((u + 0x7fffu + ((u >> 16) & 1u)) >> 16);
}
__device__ __forceinline__ float bf2f(u16 h){ return __uint_as_float(((uint)h) << 16); }
__device__ __forceinline__ float blo(uint u){ return __uint_as_float(u << 16); }
__device__ __forceinline__ float bhi(uint u){ return __uint_as_float(u & 0xffff0000u); }

// ================= one-shot prep: x cast, W0/W1 transpose, Bf build, alp2/arp2, cb =================
#define R0 (NPAD*32)
#define R1 (R0 + 256*128)
#define R2 (R1 + 128*384)
#define R3 (R2 + 256)
#define R4 (R3 + 128)
__global__ void prep_all(const float* __restrict__ x,
                         const float* __restrict__ W0, const float* __restrict__ W1,
                         const float* __restrict__ W2, const float* __restrict__ Wr,
                         const float* __restrict__ al2, const float* __restrict__ ar2,
                         const float* __restrict__ b2,
                         u16* __restrict__ Xb, u16* __restrict__ H1b,
                         u16* __restrict__ B01, u16* __restrict__ Bf,
                         float* __restrict__ alp2, float* __restrict__ arp2,
                         float* __restrict__ cb, int N)
{
    int idx = blockIdx.x * blockDim.x + threadIdx.x;
    if (idx < R0) {                                        // x: one float4 -> ushort4
        int n = idx >> 5;
        ushort4 hv = make_ushort4(0,0,0,0);
        if (n < N) {
            float4 v = ((const float4*)x)[idx];
            hv.x = f2bf(v.x); hv.y = f2bf(v.y); hv.z = f2bf(v.z); hv.w = f2bf(v.w);
        } else {
            ((ushort4*)H1b)[idx] = make_ushort4(0,0,0,0);  // zero H1 pad rows
        }
        ((ushort4*)Xb)[idx] = hv;
    } else if (idx < R1) {                                 // W0/W1 transposed bf16 [gcol][128]
        int j = idx - R0, gcol = j >> 7, k = j & 127;
        float v = (gcol < 128) ? W0[k*128 + gcol] : W1[k*128 + (gcol - 128)];
        B01[j] = f2bf(v);
    } else if (idx < R2) {                                 // Bf [128 cols][384 k]
        int j = idx - R1, c = j / 384, k = j - c*384;
        float v = 0.f;
        if (c < 97) {
            if (k < 128)      v = W2[k*194 + c];
            else if (k < 256) v = W2[(k-128)*194 + 97 + c];
            else              v = Wr[(k-256)*194 + c] + Wr[(k-256)*194 + 97 + c];
        }
        Bf[c*384 + k] = f2bf(v);
    } else if (idx < R3) {                                 // alp2/arp2 [2][128]
        int t = idx - R2, k = t & 127, h = t >> 7;
        float sl = 0.f, sr = 0.f;
        for (int d = 0; d < 97; d++) {
            float w = W2[k*194 + h*97 + d];
            sl += w * al2[h*97 + d];
            sr += w * ar2[h*97 + d];
        }
        alp2[h*128 + k] = sl;
        arp2[h*128 + k] = sr;
    } else if (idx < R4) {                                 // cb
        int c = idx - R3;
        if (c < 97) cb[c] = 0.5f * (b2[c] + b2[97 + c]);
    }
}

// ================= GEMM layers 0/1: Cc=128, fused el/er epilogue, bf16 A =================
__global__ __launch_bounds__(256, 4)
void gemm_l01(const u16* __restrict__ Ab, const u16* __restrict__ Bh, u16* __restrict__ obf,
              const float* __restrict__ alv, const float* __restrict__ arv,
              float* __restrict__ el, float* __restrict__ er, int N)
{
    __shared__ u16 sB[128 * 136];
    const int bm = blockIdx.x * 64;
    const int tid = threadIdx.x, wid = tid >> 6, lane = tid & 63;
    const int lr = lane & 15, q = lane >> 4, lk8 = q << 3;

    bf16x8 aH[4];
    {
        size_t abase = (size_t)(bm + wid*16 + lr) * 128 + lk8;
        #pragma unroll
        for (int kt = 0; kt < 4; kt++)
            aH[kt] = *(const bf16x8*)(Ab + abase + kt*32);
    }
    {
        const int c = tid >> 1, seg = (tid & 1) * 64;
        const u16* g = Bh + (size_t)c * 128 + seg;
        u16* s = sB + c * 136 + seg;
        #pragma unroll
        for (int j = 0; j < 8; j++)
            *(uint4*)(s + j*8) = *(const uint4*)(g + j*8);
    }
    __syncthreads();

    f32x4 acc[8];
    #pragma unroll
    for (int i = 0; i < 8; i++) acc[i] = (f32x4){0.f,0.f,0.f,0.f};

    #pragma unroll
    for (int kt = 0; kt < 4; kt++)
        #pragma unroll
        for (int fs = 0; fs < 8; fs++) {
            bf16x8 b = *(const bf16x8*)(sB + (fs*16 + lr)*136 + kt*32 + lk8);
            acc[fs] = __builtin_amdgcn_mfma_f32_16x16x32_bf16(aH[kt], b, acc[fs], 0, 0, 0);
        }

    float el0[4] = {0,0,0,0}, el1[4] = {0,0,0,0}, er0[4] = {0,0,0,0}, er1[4] = {0,0,0,0};
    #pragma unroll
    for (int fs = 0; fs < 8; fs++) {
        const int col = fs*16 + lr;
        const float av = alv[col], gv = arv[col];
        #pragma unroll
        for (int v = 0; v < 4; v++) {
            float f = acc[fs][v];
            int row = bm + wid*16 + q*4 + v;
            if (row < N) obf[(size_t)row * 128 + col] = f2bf(f);
            if (fs < 4) { el0[v] += f * av; er0[v] += f * gv; }
            else        { el1[v] += f * av; er1[v] += f * gv; }
        }
    }
    #pragma unroll
    for (int off = 1; off < 16; off <<= 1) {
        #pragma unroll
        for (int v = 0; v < 4; v++) {
            el0[v] += __shfl_xor(el0[v], off);
            el1[v] += __shfl_xor(el1[v], off);
            er0[v] += __shfl_xor(er0[v], off);
            er1[v] += __shfl_xor(er1[v], off);
        }
    }
    if (lr == 0) {
        #pragma unroll
        for (int v = 0; v < 4; v++) {
            int row = bm + wid*16 + q*4 + v;
            if (row < N) {
                *(float2*)(el + 2*(size_t)row) = make_float2(el0[v], el1[v]);
                *(float2*)(er + 2*(size_t)row) = make_float2(er0[v], er1[v]);
            }
        }
    }
}

// ================= final GEMM: out = 0.5*([agg0|agg1|h2] @ Bf) + cb =================
__global__ __launch_bounds__(256, 3)
void gemm_final(const u16* __restrict__ agg01, const u16* __restrict__ h2b,
                const u16* __restrict__ Bf, const float* __restrict__ cb,
                float* __restrict__ out, int N)
{
    __shared__ u16 sB[64 * 392];
    const int bid = blockIdx.x;
    const int x = (bid >> 4) * 8 + (bid & 7);
    const int ct = (bid >> 3) & 1;
    if (x >= NPAD / 64) return;                 // block-uniform
    const int bm = x * 64;
    const int tid = threadIdx.x, wid = tid >> 6, lane = tid & 63;
    const int lr = lane & 15, q = lane >> 4, lk8 = q << 3;

    bf16x8 aF[12];
    {
        const int row = bm + wid*16 + lr;
        const u16* pa = agg01 + (size_t)row * 256;
        #pragma unroll
        for (int kt = 0; kt < 8; kt++)
            aF[kt] = *(const bf16x8*)(pa + kt*32 + lk8);
        const u16* ph = h2b + (size_t)row * 128;
        #pragma unroll
        for (int kt = 0; kt < 4; kt++)
            aF[8 + kt] = *(const bf16x8*)(ph + kt*32 + lk8);
    }
    {
        const int c = tid >> 2, seg = (tid & 3) * 96;      // 96 u16 = 12 x uint4
        const u16* g = Bf + (size_t)(ct*64 + c) * 384 + seg;
        u16* s = sB + c * 392 + seg;
        #pragma unroll
        for (int j = 0; j < 12; j++)
            *(uint4*)(s + j*8) = *(const uint4*)(g + j*8);
    }
    __syncthreads();

    f32x4 acc[4];
    #pragma unroll
    for (int i = 0; i < 4; i++) acc[i] = (f32x4){0.f,0.f,0.f,0.f};

    #pragma unroll
    for (int kt = 0; kt < 12; kt++)
        #pragma unroll
        for (int fs = 0; fs < 4; fs++) {
            bf16x8 b = *(const bf16x8*)(sB + (fs*16 + lr)*392 + kt*32 + lk8);
            acc[fs] = __builtin_amdgcn_mfma_f32_16x16x32_bf16(aF[kt], b, acc[fs], 0, 0, 0);
        }

    #pragma unroll
    for (int fs = 0; fs < 4; fs++) {
        const int col = ct*64 + fs*16 + lr;
        if (col >= 97) continue;
        const float cbc = cb[col];
        #pragma unroll
        for (int v = 0; v < 4; v++) {
            int row = bm + wid*16 + q*4 + v;
            if (row < N - 1) out[(size_t)row * 97 + col] = 0.5f * acc[fs][v] + cbc;
        }
    }
}

// ================= CSR build: XCD-sliced histogram + scatter =================
// slice = blockIdx & 7 owns dst in [slice*SLICEN, (slice+1)*SLICEN): all atomics and
// scatter writes land in a 1/8 slice of cursor/ssorted -> line-dense, XCD-local.
__global__ __launch_bounds__(256)
void hist_sliced(const int* __restrict__ dst, int* __restrict__ counts, int E)
{
    const int slice = blockIdx.x & (NSLICE - 1);
    const int lo = slice * SLICEN, hi = lo + SLICEN;
    const int stride = (gridDim.x >> 3) * blockDim.x;
    for (int i = (blockIdx.x >> 3) * blockDim.x + threadIdx.x; i < E; i += stride) {
        int d = dst[i];
        if (d >= lo && d < hi) atomicAdd(&counts[d], 1);
    }
}

__global__ __launch_bounds__(256)
void scatter_sliced(const int* __restrict__ src, const int* __restrict__ dst,
                    int* __restrict__ cursor, int* __restrict__ ssorted, int E)
{
    const int slice = blockIdx.x & (NSLICE - 1);
    const int lo = slice * SLICEN, hi = lo + SLICEN;
    const int stride = (gridDim.x >> 3) * blockDim.x;
    for (int i = (blockIdx.x >> 3) * blockDim.x + threadIdx.x; i < E; i += stride) {
        int d = dst[i];
        if (d >= lo && d < hi) {
            int p = atomicAdd(&cursor[d], 1);
            ssorted[p] = src[i];
        }
    }
}

// single-pass decoupled-lookback scan; also initializes cursor (= exclusive start)
__global__ __launch_bounds__(1024)
void scan_dl(int* __restrict__ cnt_cur, int* __restrict__ row_start,
             int* __restrict__ flags, int* __restrict__ prefixes, int n)
{
    __shared__ int wsum[16];
    __shared__ int sExc;
    const int tid = threadIdx.x, lane = tid & 63, wv = tid >> 6;
    const int i0 = blockIdx.x * 4096 + tid * 4;
    int c[4], v[4];
    #pragma unroll
    for (int j = 0; j < 4; j++) { int i = i0 + j; c[j] = (i < n) ? cnt_cur[i] : 0; }
    v[0] = c[0]; v[1] = v[0] + c[1]; v[2] = v[1] + c[2]; v[3] = v[2] + c[3];
    int t = v[3];
    #pragma unroll
    for (int off = 1; off < 64; off <<= 1) {
        int u = __shfl_up(t, off);
        if (lane >= off) t += u;
    }
    int texcl = t - v[3];
    if (lane == 63) wsum[wv] = t;
    __syncthreads();
    if (tid == 0) {
        int tot = 0;
        #pragma unroll
        for (int w = 0; w < 16; w++) tot += wsum[w];
        int exc = 0;
        if (blockIdx.x > 0) {
            while (atomicAdd(&flags[blockIdx.x - 1], 0) == 0) __builtin_amdgcn_s_sleep(2);
            exc = atomicAdd(&prefixes[blockIdx.x - 1], 0);
        } else {
            row_start[0] = 0;
        }
        atomicExch(&prefixes[blockIdx.x], exc + tot);
        __threadfence();
        atomicExch(&flags[blockIdx.x], 1);
        sExc = exc;
    }
    __syncthreads();
    int woff = sExc + texcl;
    for (int w = 0; w < 16; w++) if (w < wv) woff += wsum[w];
    #pragma unroll
    for (int j = 0; j < 4; j++) {
        int i = i0 + j;
        if (i < n) {
            int inc = woff + v[j];
            row_start[i + 1] = inc;
            cnt_cur[i] = inc - c[j];                       // cursor init = exclusive start
        }
    }
}

// ================= aggregation, C=128 layers: one wave per dst node =================
// MODE 0: no res. MODE 1: residual from Rb + fused el2/er2 (= h2 . alp2/arp2) epilogue.
template<int MODE>
__global__ __launch_bounds__(256)
void gat_agg128(const uint* __restrict__ ftb, const float* __restrict__ el,
                const float* __restrict__ er, const int* __restrict__ row_start,
                const int* __restrict__ ssorted, const u16* __restrict__ Rb,
                const float* __restrict__ bias, u16* __restrict__ Hb,
                const float* __restrict__ alp2, const float* __restrict__ arp2,
                float* __restrict__ el2, float* __restrict__ er2)
{
    __shared__ int   s_src[4][64];
    __shared__ float s_w[4][2][64];
    const int wv = threadIdx.x >> 6, lane = threadIdx.x & 63;
    const int n = blockIdx.x * 4 + wv;
    const int beg = row_start[n];
    const int deg = row_start[n+1] - beg;
    const float2 ern = *(const float2*)(er + 2*(size_t)n);
    const int h = lane >> 5;
    float ax = 0.f, ay = 0.f, dp0 = 0.f, dp1 = 0.f;

    for (int cb = 0; cb < deg; cb += 64) {
        const int cnt = min(64, deg - cb);
        float w0 = 0.f, w1 = 0.f; int s = 0;
        if (lane < cnt) {
            s = ssorted[beg + cb + lane];
            float2 e = *(const float2*)(el + 2*(size_t)s);
            w0 = __expf(lrelu(e.x + ern.x));     // no max subtraction: |logit| small
            w1 = __expf(lrelu(e.y + ern.y));
        }
        dp0 += w0; dp1 += w1;
        s_src[wv][lane] = s; s_w[wv][0][lane] = w0; s_w[wv][1][lane] = w1;
        asm volatile("s_waitcnt lgkmcnt(0)" ::: "memory");   // wave-synchronous LDS publish
        int t = 0;
        for (; t + 8 <= cnt; t += 8) {
            int4   sa = *(const int4*)&s_src[wv][t];
            int4   sb = *(const int4*)&s_src[wv][t+4];
            float4 wa = *(const float4*)&s_w[wv][h][t];
            float4 wb = *(const float4*)&s_w[wv][h][t+4];
            int   sv[8] = {sa.x,sa.y,sa.z,sa.w,sb.x,sb.y,sb.z,sb.w};
            float wj[8] = {wa.x,wa.y,wa.z,wa.w,wb.x,wb.y,wb.z,wb.w};
            uint U[8];
            #pragma unroll
            for (int j = 0; j < 8; j++) U[j] = ftb[((uint)sv[j] << 6) + lane];
            #pragma unroll
            for (int j = 0; j < 8; j++) { ax += wj[j]*blo(U[j]); ay += wj[j]*bhi(U[j]); }
        }
        for (; t < cnt; t++) {
            int sv = s_src[wv][t];
            float w = s_w[wv][h][t];
            uint u = ftb[((uint)sv << 6) + lane];
            ax += w*blo(u); ay += w*bhi(u);
        }
    }
    #pragma unroll
    for (int off = 32; off; off >>= 1) { dp0 += __shfl_xor(dp0, off); dp1 += __shfl_xor(dp1, off); }
    const float den = (h == 0) ? dp0 : dp1;
    float r0 = (deg > 0) ? ax / den : 0.f;
    float r1 = (deg > 0) ? ay / den : 0.f;
    const int c0 = 2 * lane;
    const size_t ob = (size_t)n*128 + c0;
    const float2 bv = *(const float2*)(bias + c0);
    float v0 = r0 + bv.x, v1 = r1 + bv.y;
    if (MODE == 1) {
        ushort2 rv = *(const ushort2*)&Rb[ob];
        v0 += bf2f(rv.x);
        v1 += bf2f(rv.y);
    }
    v0 = elu_f(v0); v1 = elu_f(v1);
    *(ushort2*)&Hb[ob] = make_ushort2(f2bf(v0), f2bf(v1));

    if constexpr (MODE == 1) {
        float2 a0 = *(const float2*)(alp2 + c0);
        float2 a1 = *(const float2*)(alp2 + 128 + c0);
        float2 g0 = *(const float2*)(arp2 + c0);
        float2 g1 = *(const float2*)(arp2 + 128 + c0);
        float e0 = v0*a0.x + v1*a0.y;
        float e1 = v0*a1.x + v1*a1.y;
        float f0 = v0*g0.x + v1*g0.y;
        float f1 = v0*g1.x + v1*g1.y;
        #pragma unroll
        for (int off = 32; off; off >>= 1) {
            e0 += __shfl_xor(e0, off); e1 += __shfl_xor(e1, off);
            f0 += __shfl_xor(f0, off); f1 += __shfl_xor(f1, off);
        }
        if (lane == 0) {
            *(float2*)(el2 + 2*(size_t)n) = make_float2(e0, e1);
            *(float2*)(er2 + 2*(size_t)n) = make_float2(f0, f1);
        }
    }
}

// ================= layer-2 aggregation on h2 (linearity trick) =================
__global__ __launch_bounds__(256)
void gat_agg_out2(const uint* __restrict__ h2u, const float* __restrict__ el,
                  const float* __restrict__ er, const int* __restrict__ row_start,
                  const int* __restrict__ ssorted, u16* __restrict__ agg01)
{
    __shared__ int   s_src[4][64];
    __shared__ float s_w[4][2][64];
    const int wv = threadIdx.x >> 6, lane = threadIdx.x & 63;
    const int n = blockIdx.x * 4 + wv;
    const int beg = row_start[n];
    const int deg = row_start[n+1] - beg;
    const float2 ern = *(const float2*)(er + 2*(size_t)n);
    float ax0 = 0.f, ay0 = 0.f, ax1 = 0.f, ay1 = 0.f, dp0 = 0.f, dp1 = 0.f;

    for (int cb = 0; cb < deg; cb += 64) {
        const int cnt = min(64, deg - cb);
        float w0 = 0.f, w1 = 0.f; int s = 0;
        if (lane < cnt) {
            s = ssorted[beg + cb + lane];
            float2 e = *(const float2*)(el + 2*(size_t)s);
            w0 = __expf(lrelu(e.x + ern.x));
            w1 = __expf(lrelu(e.y + ern.y));
        }
        dp0 += w0; dp1 += w1;
        s_src[wv][lane] = s; s_w[wv][0][lane] = w0; s_w[wv][1][lane] = w1;
        asm volatile("s_waitcnt lgkmcnt(0)" ::: "memory");
        int t = 0;
        for (; t + 8 <= cnt; t += 8) {
            int4   sa = *(const int4*)&s_src[wv][t];
            int4   sb = *(const int4*)&s_src[wv][t+4];
            float4 p0a = *(const float4*)&s_w[wv][0][t];
            float4 p0b = *(const float4*)&s_w[wv][0][t+4];
            float4 p1a = *(const float4*)&s_w[wv][1][t];
            float4 p1b = *(const float4*)&s_w[wv][1][t+4];
            int   sv[8] = {sa.x,sa.y,sa.z,sa.w,sb.x,sb.y,sb.z,sb.w};
            float f0[8] = {p0a.x,p0a.y,p0a.z,p0a.w,p0b.x,p0b.y,p0b.z,p0b.w};
            float f1[8] = {p1a.x,p1a.y,p1a.z,p1a.w,p1b.x,p1b.y,p1b.z,p1b.w};
            uint U[8];
            #pragma unroll
            for (int j = 0; j < 8; j++) U[j] = h2u[((uint)sv[j] << 6) + lane];
            #pragma unroll
            for (int j = 0; j < 8; j++) {
                float lo = blo(U[j]), hi = bhi(U[j]);
                ax0 += f0[j]*lo; ay0 += f0[j]*hi;
                ax1 += f1[j]*lo; ay1 += f1[j]*hi;
            }
        }
        for (; t < cnt; t++) {
            int sv = s_src[wv][t];
            float f0 = s_w[wv][0][t], f1 = s_w[wv][1][t];
            uint u = h2u[((uint)sv << 6) + lane];
            float lo = blo(u), hi = bhi(u);
            ax0 += f0*lo; ay0 += f0*hi;
            ax1 += f1*lo; ay1 += f1*hi;
        }
    }
    #pragma unroll
    for (int off = 32; off; off >>= 1) { dp0 += __shfl_xor(dp0, off); dp1 += __shfl_xor(dp1, off); }
    const float i0 = (deg > 0) ? 1.f/dp0 : 0.f;
    const float i1 = (deg > 0) ? 1.f/dp1 : 0.f;
    const int c0 = 2 * lane;
    *(ushort2*)&agg01[(size_t)n*256 + c0]       = make_ushort2(f2bf(ax0*i0), f2bf(ay0*i0));
    *(ushort2*)&agg01[(size_t)n*256 + 128 + c0] = make_ushort2(f2bf(ax1*i1), f2bf(ay1*i1));
}

extern "C" void kernel_launch(void* const* d_in, const int* in_sizes, int n_in,
                              void* d_out, int out_size, void* d_ws, size_t ws_size,
                              hipStream_t stream)
{
    const float* x   = (const float*)d_in[0];
    const int*   esrc= (const int*)  d_in[1];
    const int*   edst= (const int*)  d_in[2];
    const float* W0  = (const float*)d_in[3];
    const float* al0 = (const float*)d_in[4];
    const float* ar0 = (const float*)d_in[5];
    const float* b0  = (const float*)d_in[6];
    const float* W1  = (const float*)d_in[7];
    const float* al1 = (const float*)d_in[8];
    const float* ar1 = (const float*)d_in[9];
    const float* b1  = (const float*)d_in[10];
    const float* W2  = (const float*)d_in[11];
    const float* al2 = (const float*)d_in[12];
    const float* ar2 = (const float*)d_in[13];
    const float* b2  = (const float*)d_in[14];
    const float* rW2 = (const float*)d_in[15];
    float* out = (float*)d_out;

    const int N = NNODES, E = NEDGES;
    const int NB = (N + 4095) / 4096;            // 13 scan tiles
    float* ws = (float*)d_ws;
    size_t o = 0;
    auto alloc_f = [&](size_t count) { float* p = ws + o; o += (count + 3) & ~(size_t)3; return p; };
    float* el    = alloc_f((size_t)N * 2);
    float* er    = alloc_f((size_t)N * 2);
    float* el2   = alloc_f((size_t)N * 2);
    float* er2   = alloc_f((size_t)N * 2);
    uint*  ftb   = (uint*)alloc_f((size_t)N * 64);         // bf16 ft [N][128]
    u16*   agg01 = (u16*)alloc_f((size_t)NPAD * 128);      // bf16 [NPAD][256]
    u16*   Xb    = (u16*)alloc_f((size_t)NPAD * 64);       // bf16 [NPAD][128] (x, then h2)
    u16*   H1b   = (u16*)alloc_f((size_t)NPAD * 64);
    u16*   B01   = (u16*)alloc_f(256 * 64);                // W0|W1 transposed bf16
    u16*   Bf    = (u16*)alloc_f(128 * 192);               // final-GEMM B' [128][384]
    float* alp2  = alloc_f(256);
    float* arp2  = alloc_f(256);
    float* cbv   = alloc_f(128);
    int* row_start = (int*)alloc_f(N + 4);
    int* cursor    = (int*)alloc_f(N + 64);                // counts/cursor + flags + prefixes
    int* flags     = cursor + N;
    int* prefixes  = cursor + N + 16;
    int* ssorted   = (int*)alloc_f(E);

    // ---- CSR by dst: memset, sliced hist, single-pass scan (inits cursor), sliced scatter ----
    hipMemsetAsync(cursor, 0, (N + 64) * sizeof(int), stream);
    hist_sliced<<<NSLICE * 256, 256, 0, stream>>>(edst, cursor, E);
    scan_dl<<<NB, 1024, 0, stream>>>(cursor, row_start, flags, prefixes, N);
    scatter_sliced<<<NSLICE * 256, 256, 0, stream>>>(esrc, edst, cursor, ssorted, E);

    // ---- all input prep in one kernel ----
    prep_all<<<(R4 + 255) / 256, 256, 0, stream>>>(x, W0, W1, W2, rW2, al2, ar2, b2,
                                                   Xb, H1b, B01, Bf, alp2, arp2, cbv, N);

    const int gx = NPAD / 64;                    // 782
    const int agg_grid = N / 4;                  // 12500

    // ---- layer 0 (GEMM + fused el/er) ----
    gemm_l01<<<gx, 256, 0, stream>>>(Xb, B01, (u16*)ftb, al0, ar0, el, er, N);
    gat_agg128<0><<<agg_grid, 256, 0, stream>>>(ftb, el, er, row_start, ssorted,
                                                nullptr, b0, H1b, nullptr, nullptr, nullptr, nullptr);

    // ---- layer 1 (identity residual; epilogue computes h2 + el2/er2) ----
    gemm_l01<<<gx, 256, 0, stream>>>(H1b, B01 + 128*128, (u16*)ftb, al1, ar1, el, er, N);
    gat_agg128<1><<<agg_grid, 256, 0, stream>>>(ftb, el, er, row_start, ssorted,
                                                H1b, b1, Xb, alp2, arp2, el2, er2);

    // ---- layer 2: aggregate h2 per head, then fused output GEMM ----
    gat_agg_out2<<<agg_grid, 256, 0, stream>>>((uint*)Xb, el2, er2, row_start, ssorted, agg01);
    gemm_final<<<((gx + 7) / 8) * 16, 256, 0, stream>>>(agg01, Xb, Bf, cbv, out, N);
}